// Round 1
// 1590.998 us; speedup vs baseline: 3.3927x; 3.3927x over previous
//
#include <hip/hip_runtime.h>
#include <hip/hip_bf16.h>

typedef float f32x4 __attribute__((ext_vector_type(4)));

#define N_NODES 20000
#define NGENES  2000
#define NEDGE   640000
#define EMB     128
#define ED      32
#define PD      64
#define OUTD    16
#define KEMB    2000

// ---------------- max(src) reduction ----------------
__global__ __launch_bounds__(256) void k_srcmax(const int* __restrict__ src,
                                                int* __restrict__ out) {
    __shared__ int sm[256];
    int i = blockIdx.x * 256 + threadIdx.x;
    sm[threadIdx.x] = (i < NEDGE) ? src[i] : 0;
    __syncthreads();
    for (int s = 128; s > 0; s >>= 1) {
        if (threadIdx.x < s) sm[threadIdx.x] = max(sm[threadIdx.x], sm[threadIdx.x + s]);
        __syncthreads();
    }
    if (threadIdx.x == 0) atomicMax(out, sm[0]);
}

// ---------------- CSR build: histogram / scan / scatter ----------------
__global__ __launch_bounds__(256) void k_hist(const int* __restrict__ dst,
                                              int* __restrict__ cnt) {
    int e = blockIdx.x * 256 + threadIdx.x;
    atomicAdd(&cnt[dst[e]], 1);
}

// single-block exclusive scan over 20000 bins -> row_start[0..N], cursor[i]=row_start[i]
__global__ __launch_bounds__(1024) void k_scan(const int* __restrict__ cnt,
                                               int* __restrict__ row_start,
                                               int* __restrict__ cursor) {
    __shared__ int a[1024], b[1024];
    __shared__ int carry_s;
    int tid = threadIdx.x;
    if (tid == 0) carry_s = 0;
    __syncthreads();
    for (int chunk = 0; chunk < (N_NODES + 1023) / 1024; ++chunk) {
        int i = chunk * 1024 + tid;
        int v = (i < N_NODES) ? cnt[i] : 0;
        a[tid] = v;
        __syncthreads();
        int* s_ = a; int* d_ = b;
        for (int off = 1; off < 1024; off <<= 1) {
            int val = s_[tid];
            if (tid >= off) val += s_[tid - off];
            d_[tid] = val;
            __syncthreads();
            int* t = s_; s_ = d_; d_ = t;
        }
        int incl = s_[tid];
        int carry = carry_s;
        if (i < N_NODES) {
            row_start[i + 1] = carry + incl;
            cursor[i] = carry + incl - v;   // exclusive prefix = segment start
        }
        __syncthreads();
        if (tid == 1023) carry_s = carry + incl;
        __syncthreads();
    }
    if (tid == 0) row_start[0] = 0;
}

__global__ __launch_bounds__(256) void k_scatter(const int* __restrict__ dst,
                                                 int* __restrict__ cursor,
                                                 int* __restrict__ perm) {
    int e = blockIdx.x * 256 + threadIdx.x;
    int pos = atomicAdd(&cursor[dst[e]], 1);
    perm[pos] = e;
}

// ---------------- embedding GEMM f32: h = x @ W_emb + b ----------------
__global__ __launch_bounds__(256) void k_emb_f32(const float* __restrict__ x,
                                                 const float* __restrict__ W,   // [2000][128]
                                                 const float* __restrict__ bias,
                                                 float* __restrict__ h) {
    __shared__ float As[64 * 17];
    __shared__ float Bs[16 * 64];
    int tid = threadIdx.x;
    int mt = blockIdx.x >> 1, nt = blockIdx.x & 1;
    int row0 = mt * 64, n0 = nt * 64;
    int tx = tid & 15, ty = tid >> 4;
    float acc[4][4] = {};
    int ar = tid >> 2, ac = (tid & 3) * 4;
    int bkr = tid >> 4, bc = (tid & 15) * 4;
    for (int kt = 0; kt < 125; ++kt) {
        int k0 = kt * 16;
        if (row0 + ar < N_NODES) {
            f32x4 av = *(const f32x4*)(x + (long)(row0 + ar) * KEMB + k0 + ac);
#pragma unroll
            for (int j = 0; j < 4; ++j) As[ar * 17 + ac + j] = av[j];
        } else {
#pragma unroll
            for (int j = 0; j < 4; ++j) As[ar * 17 + ac + j] = 0.f;
        }
        *(f32x4*)(Bs + bkr * 64 + bc) = *(const f32x4*)(W + (long)(k0 + bkr) * EMB + n0 + bc);
        __syncthreads();
#pragma unroll 1
        for (int kk = 0; kk < 16; ++kk) {
            float a[4];
#pragma unroll
            for (int i = 0; i < 4; ++i) a[i] = As[(ty * 4 + i) * 17 + kk];
            f32x4 b = *(const f32x4*)(Bs + kk * 64 + tx * 4);
#pragma unroll
            for (int i = 0; i < 4; ++i)
#pragma unroll
                for (int j = 0; j < 4; ++j) acc[i][j] += a[i] * b[j];
        }
        __syncthreads();
    }
#pragma unroll
    for (int i = 0; i < 4; ++i) {
        int row = row0 + ty * 4 + i;
        if (row >= N_NODES) continue;
        f32x4 o;
#pragma unroll
        for (int j = 0; j < 4; ++j) o[j] = acc[i][j] + bias[n0 + tx * 4 + j];
        *(f32x4*)(h + (long)row * EMB + n0 + tx * 4) = o;
    }
}

// ---------------- message (sorted, no atomics): m[i] = relu(cat(h[src[perm[i]]],ea) @ W + b) * P ----------------
__global__ __launch_bounds__(256) void k_msg2(const float* __restrict__ h,
                                              const float* __restrict__ ea,
                                              const int* __restrict__ src,
                                              const int* __restrict__ perm,
                                              const float* __restrict__ mW,   // [160][64]
                                              const float* __restrict__ mb,   // [64]
                                              const float* __restrict__ P,    // [2000][64]
                                              const int* __restrict__ smax,
                                              float* __restrict__ m) {
    int i = blockIdx.x * 256 + threadIdx.x;
    int e = perm[i];
    int s = src[e];
    float acc[PD];
#pragma unroll
    for (int o = 0; o < PD; ++o) acc[o] = mb[o];
#pragma unroll 1
    for (int kb = 0; kb < 10; ++kb) {
        float in[16];
        if (kb < 8) {
            f32x4 v0 = *(const f32x4*)(h + (long)s * EMB + kb * 16);
            f32x4 v1 = *(const f32x4*)(h + (long)s * EMB + kb * 16 + 4);
            f32x4 v2 = *(const f32x4*)(h + (long)s * EMB + kb * 16 + 8);
            f32x4 v3 = *(const f32x4*)(h + (long)s * EMB + kb * 16 + 12);
#pragma unroll
            for (int j = 0; j < 4; ++j) { in[j] = v0[j]; in[4+j] = v1[j]; in[8+j] = v2[j]; in[12+j] = v3[j]; }
        } else {
            f32x4 v0 = *(const f32x4*)(ea + (long)e * ED + (kb - 8) * 16);
            f32x4 v1 = *(const f32x4*)(ea + (long)e * ED + (kb - 8) * 16 + 4);
            f32x4 v2 = *(const f32x4*)(ea + (long)e * ED + (kb - 8) * 16 + 8);
            f32x4 v3 = *(const f32x4*)(ea + (long)e * ED + (kb - 8) * 16 + 12);
#pragma unroll
            for (int j = 0; j < 4; ++j) { in[j] = v0[j]; in[4+j] = v1[j]; in[8+j] = v2[j]; in[12+j] = v3[j]; }
        }
#pragma unroll 1
        for (int kk = 0; kk < 16; ++kk) {
            const float* wrow = mW + (long)(kb * 16 + kk) * PD;  // lane-uniform -> s_load
            float v = in[kk];
#pragma unroll
            for (int o = 0; o < PD; ++o) acc[o] += v * wrow[o];
        }
    }
    int base = *smax - (NGENES - 1);
    const float* Pe = P + (long)(s - base) * PD;
    float* mrow = m + (long)i * PD;
#pragma unroll
    for (int c = 0; c < 16; ++c) {
        f32x4 v;
#pragma unroll
        for (int j = 0; j < 4; ++j) v[j] = fmaxf(acc[c * 4 + j], 0.f) * Pe[c * 4 + j];
        *(f32x4*)(mrow + c * 4) = v;
    }
}

// ---------------- aggregate: one wave per node, contiguous segment sum ----------------
__global__ __launch_bounds__(256) void k_aggr(const float* __restrict__ m,
                                              const int* __restrict__ row_start,
                                              float* __restrict__ aggr) {
    int n = blockIdx.x * 4 + (threadIdx.x >> 6);
    int lane = threadIdx.x & 63;
    if (n >= N_NODES) return;
    int j0 = row_start[n], j1 = row_start[n + 1];
    float acc0 = 0.f, acc1 = 0.f;
    int j = j0;
    for (; j + 1 < j1; j += 2) {
        acc0 += m[(long)j * PD + lane];
        acc1 += m[(long)(j + 1) * PD + lane];
    }
    if (j < j1) acc0 += m[(long)j * PD + lane];
    aggr[(long)n * PD + lane] = acc0 + acc1;
}

// ---------------- fallback fused message (atomic scatter) ----------------
__global__ __launch_bounds__(256) void k_msg_f32(const float* __restrict__ h,
                                                 const float* __restrict__ ea,
                                                 const int* __restrict__ src,
                                                 const int* __restrict__ dst,
                                                 const float* __restrict__ mW,
                                                 const float* __restrict__ mb,
                                                 const float* __restrict__ P,
                                                 const int* __restrict__ smax,
                                                 float* __restrict__ aggr) {
    int e = blockIdx.x * 256 + threadIdx.x;
    int s = src[e], d = dst[e];
    float acc[PD];
#pragma unroll
    for (int o = 0; o < PD; ++o) acc[o] = mb[o];
#pragma unroll 1
    for (int kb = 0; kb < 10; ++kb) {
        float in[16];
        if (kb < 8) {
            f32x4 v0 = *(const f32x4*)(h + (long)s * EMB + kb * 16);
            f32x4 v1 = *(const f32x4*)(h + (long)s * EMB + kb * 16 + 4);
            f32x4 v2 = *(const f32x4*)(h + (long)s * EMB + kb * 16 + 8);
            f32x4 v3 = *(const f32x4*)(h + (long)s * EMB + kb * 16 + 12);
#pragma unroll
            for (int j = 0; j < 4; ++j) { in[j] = v0[j]; in[4+j] = v1[j]; in[8+j] = v2[j]; in[12+j] = v3[j]; }
        } else {
            f32x4 v0 = *(const f32x4*)(ea + (long)e * ED + (kb - 8) * 16);
            f32x4 v1 = *(const f32x4*)(ea + (long)e * ED + (kb - 8) * 16 + 4);
            f32x4 v2 = *(const f32x4*)(ea + (long)e * ED + (kb - 8) * 16 + 8);
            f32x4 v3 = *(const f32x4*)(ea + (long)e * ED + (kb - 8) * 16 + 12);
#pragma unroll
            for (int j = 0; j < 4; ++j) { in[j] = v0[j]; in[4+j] = v1[j]; in[8+j] = v2[j]; in[12+j] = v3[j]; }
        }
#pragma unroll 1
        for (int kk = 0; kk < 16; ++kk) {
            const float* wrow = mW + (long)(kb * 16 + kk) * PD;
            float v = in[kk];
#pragma unroll
            for (int o = 0; o < PD; ++o) acc[o] += v * wrow[o];
        }
    }
    int base = *smax - (NGENES - 1);
    const float* Pe = P + (long)(s - base) * PD;
    float* arow = aggr + (long)d * PD;
#pragma unroll
    for (int o = 0; o < PD; ++o) {
        float v = fmaxf(acc[o], 0.f) * Pe[o];
        unsafeAtomicAdd(arow + o, v);
    }
}

// ---------------- update f32 (in-place h): h = relu(cat(aggr,h) @ W + b) ----------------
__global__ __launch_bounds__(256) void k_upd_f32(const float* __restrict__ aggr,
                                                 float* __restrict__ h,
                                                 const float* __restrict__ uW,  // [192][128]
                                                 const float* __restrict__ ub)  // [128]
{
    __shared__ float lds[64 * 193];
    int tid = threadIdx.x;
    int n0 = blockIdx.x * 64;
    for (int i = tid; i < 64 * 64; i += 256) {
        int nl = i >> 6, k = i & 63;
        lds[nl * 193 + k] = (n0 + nl < N_NODES) ? aggr[(long)(n0 + nl) * PD + k] : 0.f;
    }
    for (int i = tid; i < 64 * 128; i += 256) {
        int nl = i >> 7, k = i & 127;
        lds[nl * 193 + 64 + k] = (n0 + nl < N_NODES) ? h[(long)(n0 + nl) * EMB + k] : 0.f;
    }
    __syncthreads();
    int wv = tid >> 6, l = tid & 63;
    int o0 = wv * 32;
    int n = n0 + l;
    float acc[32];
#pragma unroll
    for (int o = 0; o < 32; ++o) acc[o] = ub[o0 + o];
#pragma unroll 1
    for (int k = 0; k < 192; ++k) {
        float v = lds[l * 193 + k];
        const float* wrow = uW + (long)k * EMB + o0;
#pragma unroll
        for (int o = 0; o < 32; ++o) acc[o] += v * wrow[o];
    }
    if (n < N_NODES) {
#pragma unroll
        for (int c = 0; c < 8; ++c) {
            f32x4 v;
#pragma unroll
            for (int j = 0; j < 4; ++j) v[j] = fmaxf(acc[c * 4 + j], 0.f);
            *(f32x4*)(h + (long)n * EMB + o0 + c * 4) = v;
        }
    }
}

// ---------------- node head f32 ----------------
__global__ __launch_bounds__(256) void k_node_f32(const float* __restrict__ h,
                                                  const float* __restrict__ W,  // [128][16]
                                                  const float* __restrict__ b,
                                                  float* __restrict__ out) {
    int n = blockIdx.x * 256 + threadIdx.x;
    if (n >= N_NODES) return;
    float acc[OUTD];
#pragma unroll
    for (int o = 0; o < OUTD; ++o) acc[o] = b[o];
#pragma unroll 1
    for (int kb = 0; kb < 32; ++kb) {
        f32x4 hv = *(const f32x4*)(h + (long)n * EMB + kb * 4);
#pragma unroll
        for (int j = 0; j < 4; ++j) {
            const float* wrow = W + (long)(kb * 4 + j) * OUTD;
#pragma unroll
            for (int o = 0; o < OUTD; ++o) acc[o] += hv[j] * wrow[o];
        }
    }
#pragma unroll
    for (int c = 0; c < 4; ++c) {
        f32x4 v;
#pragma unroll
        for (int j = 0; j < 4; ++j) v[j] = acc[c * 4 + j];
        *(f32x4*)(out + (long)n * OUTD + c * 4) = v;
    }
}

// ---------------- edge head f32 ----------------
__global__ __launch_bounds__(256) void k_edge_f32(const float* __restrict__ h,
                                                  const float* __restrict__ ea,
                                                  const int* __restrict__ src,
                                                  const int* __restrict__ dst,
                                                  const float* __restrict__ Wep, // [288]
                                                  const float* __restrict__ bep,
                                                  float* __restrict__ out) {
    int e = blockIdx.x * 256 + threadIdx.x;
    int s = src[e], d = dst[e];
    float acc = bep[0];
#pragma unroll 1
    for (int kb = 0; kb < 32; ++kb) {
        f32x4 hv = *(const f32x4*)(h + (long)s * EMB + kb * 4);
#pragma unroll
        for (int j = 0; j < 4; ++j) acc += hv[j] * Wep[kb * 4 + j];
    }
#pragma unroll 1
    for (int kb = 0; kb < 32; ++kb) {
        f32x4 hv = *(const f32x4*)(h + (long)d * EMB + kb * 4);
#pragma unroll
        for (int j = 0; j < 4; ++j) acc += hv[j] * Wep[128 + kb * 4 + j];
    }
#pragma unroll 1
    for (int kb = 0; kb < 8; ++kb) {
        f32x4 av = *(const f32x4*)(ea + (long)e * ED + kb * 4);
#pragma unroll
        for (int j = 0; j < 4; ++j) acc += av[j] * Wep[256 + kb * 4 + j];
    }
    out[e] = acc;
}

extern "C" void kernel_launch(void* const* d_in, const int* in_sizes, int n_in,
                              void* d_out, int out_size, void* d_ws, size_t ws_size,
                              hipStream_t stream) {
    const float* x      = (const float*)d_in[0];
    const float* ea     = (const float*)d_in[1];
    const int*   eidx   = (const int*)d_in[2];
    const float* W_emb  = (const float*)d_in[3];
    const float* b_emb  = (const float*)d_in[4];
    const float* msg_W  = (const float*)d_in[5];
    const float* msg_b  = (const float*)d_in[6];
    const float* upd_W  = (const float*)d_in[7];
    const float* upd_b  = (const float*)d_in[8];
    const float* W_node = (const float*)d_in[9];
    const float* b_node = (const float*)d_in[10];
    const float* W_ep   = (const float*)d_in[11];
    const float* b_ep   = (const float*)d_in[12];
    const float* P      = (const float*)d_in[13];
    float* out = (float*)d_out;

    const int* src = eidx;
    const int* dst = eidx + NEDGE;

    // ---- workspace layout ----
    size_t off = 0;
    char* w = (char*)d_ws;
    float* h    = (float*)(w + off); off += (size_t)N_NODES * EMB * 4;   // 10.24 MB
    float* aggr = (float*)(w + off); off += (size_t)N_NODES * PD * 4;    // 5.12 MB
    int*   smax = (int*)(w + off);   off += 16;
    if (ws_size < off) return;

    // extended (sorted, atomic-free) layout
    size_t off2 = off;
    int* cnt       = (int*)(w + off2); off2 += (size_t)N_NODES * 4;        // 80 KB
    int* row_start = (int*)(w + off2); off2 += ((size_t)(N_NODES + 1) * 4 + 15) & ~15ull;
    int* cursor    = (int*)(w + off2); off2 += (size_t)N_NODES * 4;        // 80 KB
    int* perm      = (int*)(w + off2); off2 += (size_t)NEDGE * 4;          // 2.56 MB
    float* mbuf    = (float*)(w + off2); off2 += (size_t)NEDGE * PD * 4;   // 163.84 MB
    const bool fast = (ws_size >= off2);

    hipMemsetAsync(smax, 0, 4, stream);
    k_srcmax<<<NEDGE / 256, 256, 0, stream>>>(src, smax);

    if (fast) {
        // one-time CSR build (dst constant across both layers)
        hipMemsetAsync(cnt, 0, (size_t)N_NODES * 4, stream);
        k_hist<<<NEDGE / 256, 256, 0, stream>>>(dst, cnt);
        k_scan<<<1, 1024, 0, stream>>>(cnt, row_start, cursor);
        k_scatter<<<NEDGE / 256, 256, 0, stream>>>(dst, cursor, perm);
    }

    k_emb_f32<<<313 * 2, 256, 0, stream>>>(x, W_emb, b_emb, h);

    if (fast) {
        // layer 0
        k_msg2<<<NEDGE / 256, 256, 0, stream>>>(h, ea, src, perm, msg_W, msg_b, P, smax, mbuf);
        k_aggr<<<(N_NODES + 3) / 4, 256, 0, stream>>>(mbuf, row_start, aggr);
        k_upd_f32<<<313, 256, 0, stream>>>(aggr, h, upd_W, upd_b);
        // layer 1
        k_msg2<<<NEDGE / 256, 256, 0, stream>>>(h, ea, src, perm,
                                                msg_W + 160 * PD, msg_b + PD, P, smax, mbuf);
        k_aggr<<<(N_NODES + 3) / 4, 256, 0, stream>>>(mbuf, row_start, aggr);
        k_upd_f32<<<313, 256, 0, stream>>>(aggr, h, upd_W + 192 * EMB, upd_b + EMB);
    } else {
        // fallback: atomic scatter (old path)
        hipMemsetAsync(aggr, 0, (size_t)N_NODES * PD * 4, stream);
        k_msg_f32<<<NEDGE / 256, 256, 0, stream>>>(h, ea, src, dst, msg_W, msg_b, P, smax, aggr);
        k_upd_f32<<<313, 256, 0, stream>>>(aggr, h, upd_W, upd_b);
        hipMemsetAsync(aggr, 0, (size_t)N_NODES * PD * 4, stream);
        k_msg_f32<<<NEDGE / 256, 256, 0, stream>>>(h, ea, src, dst,
                                                   msg_W + 160 * PD, msg_b + PD, P, smax, aggr);
        k_upd_f32<<<313, 256, 0, stream>>>(aggr, h, upd_W + 192 * EMB, upd_b + EMB);
    }

    k_node_f32<<<(N_NODES + 255) / 256, 256, 0, stream>>>(h, W_node, b_node, out);
    k_edge_f32<<<NEDGE / 256, 256, 0, stream>>>(h, ea, src, dst, W_ep, b_ep,
                                                out + (size_t)N_NODES * OUTD);
}

// Round 3
// 1485.357 us; speedup vs baseline: 3.6340x; 1.0711x over previous
//
#include <hip/hip_runtime.h>
#include <hip/hip_bf16.h>

typedef float f32x4 __attribute__((ext_vector_type(4)));

#define N_NODES 20000
#define NGENES  2000
#define NEDGE   640000
#define EMB     128
#define ED      32
#define PD      64
#define OUTD    16
#define KEMB    2000

// ---------------- fused: max(src) + dst histogram ----------------
__global__ __launch_bounds__(256) void k_prep(const int* __restrict__ src,
                                              const int* __restrict__ dst,
                                              int* __restrict__ smax,
                                              int* __restrict__ cnt) {
    __shared__ int sm[256];
    int i = blockIdx.x * 256 + threadIdx.x;
    int s = src[i];
    atomicAdd(&cnt[dst[i]], 1);
    sm[threadIdx.x] = s;
    __syncthreads();
    for (int st = 128; st > 0; st >>= 1) {
        if (threadIdx.x < st) sm[threadIdx.x] = max(sm[threadIdx.x], sm[threadIdx.x + st]);
        __syncthreads();
    }
    if (threadIdx.x == 0) atomicMax(smax, sm[0]);
}

// ---------------- fallback srcmax ----------------
__global__ __launch_bounds__(256) void k_srcmax(const int* __restrict__ src,
                                                int* __restrict__ out) {
    __shared__ int sm[256];
    int i = blockIdx.x * 256 + threadIdx.x;
    sm[threadIdx.x] = (i < NEDGE) ? src[i] : 0;
    __syncthreads();
    for (int s = 128; s > 0; s >>= 1) {
        if (threadIdx.x < s) sm[threadIdx.x] = max(sm[threadIdx.x], sm[threadIdx.x + s]);
        __syncthreads();
    }
    if (threadIdx.x == 0) atomicMax(out, sm[0]);
}

// single-block exclusive scan over 20000 bins -> row_start[0..N], cursor[i]=row_start[i]
__global__ __launch_bounds__(1024) void k_scan(const int* __restrict__ cnt,
                                               int* __restrict__ row_start,
                                               int* __restrict__ cursor) {
    __shared__ int a[1024], b[1024];
    __shared__ int carry_s;
    int tid = threadIdx.x;
    if (tid == 0) carry_s = 0;
    __syncthreads();
    for (int chunk = 0; chunk < (N_NODES + 1023) / 1024; ++chunk) {
        int i = chunk * 1024 + tid;
        int v = (i < N_NODES) ? cnt[i] : 0;
        a[tid] = v;
        __syncthreads();
        int* s_ = a; int* d_ = b;
        for (int off = 1; off < 1024; off <<= 1) {
            int val = s_[tid];
            if (tid >= off) val += s_[tid - off];
            d_[tid] = val;
            __syncthreads();
            int* t = s_; s_ = d_; d_ = t;
        }
        int incl = s_[tid];
        int carry = carry_s;
        if (i < N_NODES) {
            row_start[i + 1] = carry + incl;
            cursor[i] = carry + incl - v;
        }
        __syncthreads();
        if (tid == 1023) carry_s = carry + incl;
        __syncthreads();
    }
    if (tid == 0) row_start[0] = 0;
}

__global__ __launch_bounds__(256) void k_scatter(const int* __restrict__ dst,
                                                 int* __restrict__ cursor,
                                                 int* __restrict__ perm) {
    int e = blockIdx.x * 256 + threadIdx.x;
    int pos = atomicAdd(&cursor[dst[e]], 1);
    perm[pos] = e;
}

// ---------------- K-split embedding GEMM: hpart[ks] = x[:,ksel] @ W[ksel,:] ----------------
// grid 2504 = 313 mt x 2 nt x 4 ks; full occupancy (8 blocks/CU).
__global__ __launch_bounds__(256) void k_emb_part(const float* __restrict__ x,
                                                  const float* __restrict__ W,   // [2000][128]
                                                  float* __restrict__ hpart) {
    __shared__ float As[64 * 17];
    __shared__ float Bs[16 * 64];
    int tid = threadIdx.x;
    int b = blockIdx.x;
    int ks = b & 3, nt = (b >> 2) & 1, mt = b >> 3;
    int row0 = mt * 64, n0 = nt * 64;
    int kt0 = ks * 32, kt1 = min(125, kt0 + 32);
    int tx = tid & 15, ty = tid >> 4;
    float acc[4][4] = {};
    int ar = tid >> 2, ac = (tid & 3) * 4;
    int bkr = tid >> 4, bc = (tid & 15) * 4;
    for (int kt = kt0; kt < kt1; ++kt) {
        int k0 = kt * 16;
        if (row0 + ar < N_NODES) {
            f32x4 av = *(const f32x4*)(x + (long)(row0 + ar) * KEMB + k0 + ac);
#pragma unroll
            for (int j = 0; j < 4; ++j) As[ar * 17 + ac + j] = av[j];
        } else {
#pragma unroll
            for (int j = 0; j < 4; ++j) As[ar * 17 + ac + j] = 0.f;
        }
        *(f32x4*)(Bs + bkr * 64 + bc) = *(const f32x4*)(W + (long)(k0 + bkr) * EMB + n0 + bc);
        __syncthreads();
#pragma unroll 1
        for (int kk = 0; kk < 16; ++kk) {
            float a[4];
#pragma unroll
            for (int i = 0; i < 4; ++i) a[i] = As[(ty * 4 + i) * 17 + kk];
            f32x4 bv = *(const f32x4*)(Bs + kk * 64 + tx * 4);
#pragma unroll
            for (int i = 0; i < 4; ++i)
#pragma unroll
                for (int j = 0; j < 4; ++j) acc[i][j] += a[i] * bv[j];
        }
        __syncthreads();
    }
    float* hp = hpart + (size_t)ks * N_NODES * EMB;
#pragma unroll
    for (int i = 0; i < 4; ++i) {
        int row = row0 + ty * 4 + i;
        if (row >= N_NODES) continue;
        f32x4 o;
#pragma unroll
        for (int j = 0; j < 4; ++j) o[j] = acc[i][j];
        *(f32x4*)(hp + (long)row * EMB + n0 + tx * 4) = o;
    }
}

// h = sum_{ks} hpart[ks] + bias  (deterministic)
__global__ __launch_bounds__(256) void k_emb_reduce(const float* __restrict__ hpart,
                                                    const float* __restrict__ bias,
                                                    float* __restrict__ h) {
    long i = (long)blockIdx.x * 256 + threadIdx.x;   // f32x4 index
    long p = i * 4;
    int c = (int)(p & 127);
    f32x4 a0 = *(const f32x4*)(hpart + p);
    f32x4 a1 = *(const f32x4*)(hpart + (size_t)N_NODES * EMB + p);
    f32x4 a2 = *(const f32x4*)(hpart + 2 * (size_t)N_NODES * EMB + p);
    f32x4 a3 = *(const f32x4*)(hpart + 3 * (size_t)N_NODES * EMB + p);
    f32x4 bb = *(const f32x4*)(bias + c);
    f32x4 o;
#pragma unroll
    for (int j = 0; j < 4; ++j) o[j] = (a0[j] + a1[j]) + (a2[j] + a3[j]) + bb[j];
    *(f32x4*)(h + p) = o;
}

// ---------------- fallback monolithic embedding GEMM ----------------
__global__ __launch_bounds__(256) void k_emb_f32(const float* __restrict__ x,
                                                 const float* __restrict__ W,
                                                 const float* __restrict__ bias,
                                                 float* __restrict__ h) {
    __shared__ float As[64 * 17];
    __shared__ float Bs[16 * 64];
    int tid = threadIdx.x;
    int mt = blockIdx.x >> 1, nt = blockIdx.x & 1;
    int row0 = mt * 64, n0 = nt * 64;
    int tx = tid & 15, ty = tid >> 4;
    float acc[4][4] = {};
    int ar = tid >> 2, ac = (tid & 3) * 4;
    int bkr = tid >> 4, bc = (tid & 15) * 4;
    for (int kt = 0; kt < 125; ++kt) {
        int k0 = kt * 16;
        if (row0 + ar < N_NODES) {
            f32x4 av = *(const f32x4*)(x + (long)(row0 + ar) * KEMB + k0 + ac);
#pragma unroll
            for (int j = 0; j < 4; ++j) As[ar * 17 + ac + j] = av[j];
        } else {
#pragma unroll
            for (int j = 0; j < 4; ++j) As[ar * 17 + ac + j] = 0.f;
        }
        *(f32x4*)(Bs + bkr * 64 + bc) = *(const f32x4*)(W + (long)(k0 + bkr) * EMB + n0 + bc);
        __syncthreads();
#pragma unroll 1
        for (int kk = 0; kk < 16; ++kk) {
            float a[4];
#pragma unroll
            for (int i = 0; i < 4; ++i) a[i] = As[(ty * 4 + i) * 17 + kk];
            f32x4 bv = *(const f32x4*)(Bs + kk * 64 + tx * 4);
#pragma unroll
            for (int i = 0; i < 4; ++i)
#pragma unroll
                for (int j = 0; j < 4; ++j) acc[i][j] += a[i] * bv[j];
        }
        __syncthreads();
    }
#pragma unroll
    for (int i = 0; i < 4; ++i) {
        int row = row0 + ty * 4 + i;
        if (row >= N_NODES) continue;
        f32x4 o;
#pragma unroll
        for (int j = 0; j < 4; ++j) o[j] = acc[i][j] + bias[n0 + tx * 4 + j];
        *(f32x4*)(h + (long)row * EMB + n0 + tx * 4) = o;
    }
}

// ---------------- message (sorted, no atomics) ----------------
__global__ __launch_bounds__(256) void k_msg2(const float* __restrict__ h,
                                              const float* __restrict__ ea,
                                              const int* __restrict__ src,
                                              const int* __restrict__ perm,
                                              const float* __restrict__ mW,   // [160][64]
                                              const float* __restrict__ mb,   // [64]
                                              const float* __restrict__ P,    // [2000][64]
                                              const int* __restrict__ smax,
                                              float* __restrict__ m) {
    int i = blockIdx.x * 256 + threadIdx.x;
    int e = perm[i];
    int s = src[e];
    float acc[PD];
#pragma unroll
    for (int o = 0; o < PD; ++o) acc[o] = mb[o];
#pragma unroll 1
    for (int kb = 0; kb < 10; ++kb) {
        float in[16];
        if (kb < 8) {
            f32x4 v0 = *(const f32x4*)(h + (long)s * EMB + kb * 16);
            f32x4 v1 = *(const f32x4*)(h + (long)s * EMB + kb * 16 + 4);
            f32x4 v2 = *(const f32x4*)(h + (long)s * EMB + kb * 16 + 8);
            f32x4 v3 = *(const f32x4*)(h + (long)s * EMB + kb * 16 + 12);
#pragma unroll
            for (int j = 0; j < 4; ++j) { in[j] = v0[j]; in[4+j] = v1[j]; in[8+j] = v2[j]; in[12+j] = v3[j]; }
        } else {
            f32x4 v0 = *(const f32x4*)(ea + (long)e * ED + (kb - 8) * 16);
            f32x4 v1 = *(const f32x4*)(ea + (long)e * ED + (kb - 8) * 16 + 4);
            f32x4 v2 = *(const f32x4*)(ea + (long)e * ED + (kb - 8) * 16 + 8);
            f32x4 v3 = *(const f32x4*)(ea + (long)e * ED + (kb - 8) * 16 + 12);
#pragma unroll
            for (int j = 0; j < 4; ++j) { in[j] = v0[j]; in[4+j] = v1[j]; in[8+j] = v2[j]; in[12+j] = v3[j]; }
        }
#pragma unroll 1
        for (int kk = 0; kk < 16; ++kk) {
            const float* wrow = mW + (long)(kb * 16 + kk) * PD;
            float v = in[kk];
#pragma unroll
            for (int o = 0; o < PD; ++o) acc[o] += v * wrow[o];
        }
    }
    int base = *smax - (NGENES - 1);
    const float* Pe = P + (long)(s - base) * PD;
    float* mrow = m + (long)i * PD;
#pragma unroll
    for (int c = 0; c < 16; ++c) {
        f32x4 v;
#pragma unroll
        for (int j = 0; j < 4; ++j) v[j] = fmaxf(acc[c * 4 + j], 0.f) * Pe[c * 4 + j];
        *(f32x4*)(mrow + c * 4) = v;
    }
}

// ---------------- aggregate: one wave per node, contiguous segment sum ----------------
__global__ __launch_bounds__(256) void k_aggr(const float* __restrict__ m,
                                              const int* __restrict__ row_start,
                                              float* __restrict__ aggr) {
    int n = blockIdx.x * 4 + (threadIdx.x >> 6);
    int lane = threadIdx.x & 63;
    if (n >= N_NODES) return;
    int j0 = row_start[n], j1 = row_start[n + 1];
    float acc0 = 0.f, acc1 = 0.f;
    int j = j0;
    for (; j + 1 < j1; j += 2) {
        acc0 += m[(long)j * PD + lane];
        acc1 += m[(long)(j + 1) * PD + lane];
    }
    if (j < j1) acc0 += m[(long)j * PD + lane];
    aggr[(long)n * PD + lane] = acc0 + acc1;
}

// ---------------- fallback fused message (atomic scatter) ----------------
__global__ __launch_bounds__(256) void k_msg_f32(const float* __restrict__ h,
                                                 const float* __restrict__ ea,
                                                 const int* __restrict__ src,
                                                 const int* __restrict__ dst,
                                                 const float* __restrict__ mW,
                                                 const float* __restrict__ mb,
                                                 const float* __restrict__ P,
                                                 const int* __restrict__ smax,
                                                 float* __restrict__ aggr) {
    int e = blockIdx.x * 256 + threadIdx.x;
    int s = src[e], d = dst[e];
    float acc[PD];
#pragma unroll
    for (int o = 0; o < PD; ++o) acc[o] = mb[o];
#pragma unroll 1
    for (int kb = 0; kb < 10; ++kb) {
        float in[16];
        if (kb < 8) {
            f32x4 v0 = *(const f32x4*)(h + (long)s * EMB + kb * 16);
            f32x4 v1 = *(const f32x4*)(h + (long)s * EMB + kb * 16 + 4);
            f32x4 v2 = *(const f32x4*)(h + (long)s * EMB + kb * 16 + 8);
            f32x4 v3 = *(const f32x4*)(h + (long)s * EMB + kb * 16 + 12);
#pragma unroll
            for (int j = 0; j < 4; ++j) { in[j] = v0[j]; in[4+j] = v1[j]; in[8+j] = v2[j]; in[12+j] = v3[j]; }
        } else {
            f32x4 v0 = *(const f32x4*)(ea + (long)e * ED + (kb - 8) * 16);
            f32x4 v1 = *(const f32x4*)(ea + (long)e * ED + (kb - 8) * 16 + 4);
            f32x4 v2 = *(const f32x4*)(ea + (long)e * ED + (kb - 8) * 16 + 8);
            f32x4 v3 = *(const f32x4*)(ea + (long)e * ED + (kb - 8) * 16 + 12);
#pragma unroll
            for (int j = 0; j < 4; ++j) { in[j] = v0[j]; in[4+j] = v1[j]; in[8+j] = v2[j]; in[12+j] = v3[j]; }
        }
#pragma unroll 1
        for (int kk = 0; kk < 16; ++kk) {
            const float* wrow = mW + (long)(kb * 16 + kk) * PD;
            float v = in[kk];
#pragma unroll
            for (int o = 0; o < PD; ++o) acc[o] += v * wrow[o];
        }
    }
    int base = *smax - (NGENES - 1);
    const float* Pe = P + (long)(s - base) * PD;
    float* arow = aggr + (long)d * PD;
#pragma unroll
    for (int o = 0; o < PD; ++o) {
        float v = fmaxf(acc[o], 0.f) * Pe[o];
        unsafeAtomicAdd(arow + o, v);
    }
}

// ---------------- update f32 (in-place h): h = relu(cat(aggr,h) @ W + b) ----------------
// 512 threads = 8 waves; wave wv computes outputs [wv*16, wv*16+16) for 64 nodes.
__global__ __launch_bounds__(512) void k_upd_f32(const float* __restrict__ aggr,
                                                 float* __restrict__ h,
                                                 const float* __restrict__ uW,  // [192][128]
                                                 const float* __restrict__ ub)  // [128]
{
    __shared__ float lds[64 * 193];
    int tid = threadIdx.x;
    int n0 = blockIdx.x * 64;
    for (int i = tid; i < 64 * 64; i += 512) {
        int nl = i >> 6, k = i & 63;
        lds[nl * 193 + k] = (n0 + nl < N_NODES) ? aggr[(long)(n0 + nl) * PD + k] : 0.f;
    }
    for (int i = tid; i < 64 * 128; i += 512) {
        int nl = i >> 7, k = i & 127;
        lds[nl * 193 + 64 + k] = (n0 + nl < N_NODES) ? h[(long)(n0 + nl) * EMB + k] : 0.f;
    }
    __syncthreads();
    int wv = tid >> 6, l = tid & 63;
    int o0 = wv * 16;
    int n = n0 + l;
    float acc[16];
#pragma unroll
    for (int o = 0; o < 16; ++o) acc[o] = ub[o0 + o];
#pragma unroll 4
    for (int k = 0; k < 192; ++k) {
        float v = lds[l * 193 + k];
        const float* wrow = uW + (long)k * EMB + o0;
#pragma unroll
        for (int o = 0; o < 16; ++o) acc[o] += v * wrow[o];
    }
    if (n < N_NODES) {
#pragma unroll
        for (int c = 0; c < 4; ++c) {
            f32x4 v;
#pragma unroll
            for (int j = 0; j < 4; ++j) v[j] = fmaxf(acc[c * 4 + j], 0.f);
            *(f32x4*)(h + (long)n * EMB + o0 + c * 4) = v;
        }
    }
}

// ---------------- node head f32 ----------------
__global__ __launch_bounds__(256) void k_node_f32(const float* __restrict__ h,
                                                  const float* __restrict__ W,  // [128][16]
                                                  const float* __restrict__ b,
                                                  float* __restrict__ out) {
    int n = blockIdx.x * 256 + threadIdx.x;
    if (n >= N_NODES) return;
    float acc[OUTD];
#pragma unroll
    for (int o = 0; o < OUTD; ++o) acc[o] = b[o];
#pragma unroll 1
    for (int kb = 0; kb < 32; ++kb) {
        f32x4 hv = *(const f32x4*)(h + (long)n * EMB + kb * 4);
#pragma unroll
        for (int j = 0; j < 4; ++j) {
            const float* wrow = W + (long)(kb * 4 + j) * OUTD;
#pragma unroll
            for (int o = 0; o < OUTD; ++o) acc[o] += hv[j] * wrow[o];
        }
    }
#pragma unroll
    for (int c = 0; c < 4; ++c) {
        f32x4 v;
#pragma unroll
        for (int j = 0; j < 4; ++j) v[j] = acc[c * 4 + j];
        *(f32x4*)(out + (long)n * OUTD + c * 4) = v;
    }
}

// ---------------- edge head f32 (4 independent accumulators) ----------------
__global__ __launch_bounds__(256) void k_edge_f32(const float* __restrict__ h,
                                                  const float* __restrict__ ea,
                                                  const int* __restrict__ src,
                                                  const int* __restrict__ dst,
                                                  const float* __restrict__ Wep, // [288]
                                                  const float* __restrict__ bep,
                                                  float* __restrict__ out) {
    int e = blockIdx.x * 256 + threadIdx.x;
    int s = src[e], d = dst[e];
    float a0 = bep[0], a1 = 0.f, a2 = 0.f, a3 = 0.f;
#pragma unroll 1
    for (int kb = 0; kb < 32; ++kb) {
        f32x4 hv = *(const f32x4*)(h + (long)s * EMB + kb * 4);
        a0 += hv[0] * Wep[kb * 4 + 0];
        a1 += hv[1] * Wep[kb * 4 + 1];
        a2 += hv[2] * Wep[kb * 4 + 2];
        a3 += hv[3] * Wep[kb * 4 + 3];
    }
#pragma unroll 1
    for (int kb = 0; kb < 32; ++kb) {
        f32x4 hv = *(const f32x4*)(h + (long)d * EMB + kb * 4);
        a0 += hv[0] * Wep[128 + kb * 4 + 0];
        a1 += hv[1] * Wep[128 + kb * 4 + 1];
        a2 += hv[2] * Wep[128 + kb * 4 + 2];
        a3 += hv[3] * Wep[128 + kb * 4 + 3];
    }
#pragma unroll 1
    for (int kb = 0; kb < 8; ++kb) {
        f32x4 av = *(const f32x4*)(ea + (long)e * ED + kb * 4);
        a0 += av[0] * Wep[256 + kb * 4 + 0];
        a1 += av[1] * Wep[256 + kb * 4 + 1];
        a2 += av[2] * Wep[256 + kb * 4 + 2];
        a3 += av[3] * Wep[256 + kb * 4 + 3];
    }
    out[e] = (a0 + a1) + (a2 + a3);
}

extern "C" void kernel_launch(void* const* d_in, const int* in_sizes, int n_in,
                              void* d_out, int out_size, void* d_ws, size_t ws_size,
                              hipStream_t stream) {
    const float* x      = (const float*)d_in[0];
    const float* ea     = (const float*)d_in[1];
    const int*   eidx   = (const int*)d_in[2];
    const float* W_emb  = (const float*)d_in[3];
    const float* b_emb  = (const float*)d_in[4];
    const float* msg_W  = (const float*)d_in[5];
    const float* msg_b  = (const float*)d_in[6];
    const float* upd_W  = (const float*)d_in[7];
    const float* upd_b  = (const float*)d_in[8];
    const float* W_node = (const float*)d_in[9];
    const float* b_node = (const float*)d_in[10];
    const float* W_ep   = (const float*)d_in[11];
    const float* b_ep   = (const float*)d_in[12];
    const float* P      = (const float*)d_in[13];
    float* out = (float*)d_out;

    const int* src = eidx;
    const int* dst = eidx + NEDGE;

    // ---- workspace layout ----
    size_t off = 0;
    char* w = (char*)d_ws;
    float* h    = (float*)(w + off); off += (size_t)N_NODES * EMB * 4;   // 10.24 MB
    float* aggr = (float*)(w + off); off += (size_t)N_NODES * PD * 4;    // 5.12 MB
    int*   smax = (int*)(w + off);   off += 16;
    if (ws_size < off) return;

    // extended (sorted, atomic-free) layout
    size_t off2 = off;
    int* cnt       = (int*)(w + off2); off2 += (size_t)N_NODES * 4;
    int* row_start = (int*)(w + off2); off2 += ((size_t)(N_NODES + 1) * 4 + 15) & ~15ull;
    int* cursor    = (int*)(w + off2); off2 += (size_t)N_NODES * 4;
    int* perm      = (int*)(w + off2); off2 += (size_t)NEDGE * 4;
    float* mbuf    = (float*)(w + off2); off2 += (size_t)NEDGE * PD * 4;   // 163.84 MB (also hpart scratch)
    const bool fast = (ws_size >= off2);

    hipMemsetAsync(smax, 0, 4, stream);

    if (fast) {
        // one-time CSR build (dst constant across both layers); fused srcmax+hist
        hipMemsetAsync(cnt, 0, (size_t)N_NODES * 4, stream);
        k_prep<<<NEDGE / 256, 256, 0, stream>>>(src, dst, smax, cnt);
        k_scan<<<1, 1024, 0, stream>>>(cnt, row_start, cursor);
        k_scatter<<<NEDGE / 256, 256, 0, stream>>>(dst, cursor, perm);

        // K-split embedding GEMM into mbuf (free until msg2), then reduce+bias
        k_emb_part<<<313 * 8, 256, 0, stream>>>(x, W_emb, mbuf);
        k_emb_reduce<<<2500, 256, 0, stream>>>(mbuf, b_emb, h);

        // layer 0
        k_msg2<<<NEDGE / 256, 256, 0, stream>>>(h, ea, src, perm, msg_W, msg_b, P, smax, mbuf);
        k_aggr<<<(N_NODES + 3) / 4, 256, 0, stream>>>(mbuf, row_start, aggr);
        k_upd_f32<<<313, 512, 0, stream>>>(aggr, h, upd_W, upd_b);
        // layer 1
        k_msg2<<<NEDGE / 256, 256, 0, stream>>>(h, ea, src, perm,
                                                msg_W + 160 * PD, msg_b + PD, P, smax, mbuf);
        k_aggr<<<(N_NODES + 3) / 4, 256, 0, stream>>>(mbuf, row_start, aggr);
        k_upd_f32<<<313, 512, 0, stream>>>(aggr, h, upd_W + 192 * EMB, upd_b + EMB);
    } else {
        // fallback: atomic scatter (old path)
        k_srcmax<<<NEDGE / 256, 256, 0, stream>>>(src, smax);
        k_emb_f32<<<313 * 2, 256, 0, stream>>>(x, W_emb, b_emb, h);
        hipMemsetAsync(aggr, 0, (size_t)N_NODES * PD * 4, stream);
        k_msg_f32<<<NEDGE / 256, 256, 0, stream>>>(h, ea, src, dst, msg_W, msg_b, P, smax, aggr);
        k_upd_f32<<<313, 512, 0, stream>>>(aggr, h, upd_W, upd_b);
        hipMemsetAsync(aggr, 0, (size_t)N_NODES * PD * 4, stream);
        k_msg_f32<<<NEDGE / 256, 256, 0, stream>>>(h, ea, src, dst,
                                                   msg_W + 160 * PD, msg_b + PD, P, smax, aggr);
        k_upd_f32<<<313, 512, 0, stream>>>(aggr, h, upd_W + 192 * EMB, upd_b + EMB);
    }

    k_node_f32<<<(N_NODES + 255) / 256, 256, 0, stream>>>(h, W_node, b_node, out);
    k_edge_f32<<<NEDGE / 256, 256, 0, stream>>>(h, ea, src, dst, W_ep, b_ep,
                                                out + (size_t)N_NODES * OUTD);
}

// Round 4
// 1360.527 us; speedup vs baseline: 3.9674x; 1.0918x over previous
//
#include <hip/hip_runtime.h>
#include <hip/hip_bf16.h>

typedef float f32x4 __attribute__((ext_vector_type(4)));

#define N_NODES 20000
#define NGENES  2000
#define NEDGE   640000
#define EMB     128
#define ED      32
#define PD      64
#define OUTD    16
#define KEMB    2000
#define MBLK    128   // edges per fused msg+aggr block

// ---------------- fused: max(src) + dst histogram ----------------
__global__ __launch_bounds__(256) void k_prep(const int* __restrict__ src,
                                              const int* __restrict__ dst,
                                              int* __restrict__ smax,
                                              int* __restrict__ cnt) {
    __shared__ int sm[256];
    int i = blockIdx.x * 256 + threadIdx.x;
    int s = src[i];
    atomicAdd(&cnt[dst[i]], 1);
    sm[threadIdx.x] = s;
    __syncthreads();
    for (int st = 128; st > 0; st >>= 1) {
        if (threadIdx.x < st) sm[threadIdx.x] = max(sm[threadIdx.x], sm[threadIdx.x + st]);
        __syncthreads();
    }
    if (threadIdx.x == 0) atomicMax(smax, sm[0]);
}

// ---------------- fallback srcmax ----------------
__global__ __launch_bounds__(256) void k_srcmax(const int* __restrict__ src,
                                                int* __restrict__ out) {
    __shared__ int sm[256];
    int i = blockIdx.x * 256 + threadIdx.x;
    sm[threadIdx.x] = (i < NEDGE) ? src[i] : 0;
    __syncthreads();
    for (int s = 128; s > 0; s >>= 1) {
        if (threadIdx.x < s) sm[threadIdx.x] = max(sm[threadIdx.x], sm[threadIdx.x + s]);
        __syncthreads();
    }
    if (threadIdx.x == 0) atomicMax(out, sm[0]);
}

// single-block exclusive scan over 20000 bins -> row_start[0..N], cursor[i]=row_start[i]
__global__ __launch_bounds__(1024) void k_scan(const int* __restrict__ cnt,
                                               int* __restrict__ row_start,
                                               int* __restrict__ cursor) {
    __shared__ int a[1024], b[1024];
    __shared__ int carry_s;
    int tid = threadIdx.x;
    if (tid == 0) carry_s = 0;
    __syncthreads();
    for (int chunk = 0; chunk < (N_NODES + 1023) / 1024; ++chunk) {
        int i = chunk * 1024 + tid;
        int v = (i < N_NODES) ? cnt[i] : 0;
        a[tid] = v;
        __syncthreads();
        int* s_ = a; int* d_ = b;
        for (int off = 1; off < 1024; off <<= 1) {
            int val = s_[tid];
            if (tid >= off) val += s_[tid - off];
            d_[tid] = val;
            __syncthreads();
            int* t = s_; s_ = d_; d_ = t;
        }
        int incl = s_[tid];
        int carry = carry_s;
        if (i < N_NODES) {
            row_start[i + 1] = carry + incl;
            cursor[i] = carry + incl - v;
        }
        __syncthreads();
        if (tid == 1023) carry_s = carry + incl;
        __syncthreads();
    }
    if (tid == 0) row_start[0] = 0;
}

__global__ __launch_bounds__(256) void k_scatter(const int* __restrict__ dst,
                                                 int* __restrict__ cursor,
                                                 int* __restrict__ perm) {
    int e = blockIdx.x * 256 + threadIdx.x;
    int pos = atomicAdd(&cursor[dst[e]], 1);
    perm[pos] = e;
}

// ---------------- gather edge data into sorted order (once) ----------------
__global__ __launch_bounds__(256) void k_gather(const float* __restrict__ ea,
                                                const int* __restrict__ src,
                                                const int* __restrict__ dstv,
                                                const int* __restrict__ perm,
                                                float* __restrict__ ea_s,
                                                int* __restrict__ src_s,
                                                int* __restrict__ dst_s) {
    int i = blockIdx.x * 256 + threadIdx.x;
    int e = perm[i];
    src_s[i] = src[e];
    dst_s[i] = dstv[e];
    const f32x4* a = (const f32x4*)(ea + (long)e * ED);
    f32x4* o = (f32x4*)(ea_s + (long)i * ED);
#pragma unroll
    for (int c = 0; c < 8; ++c) o[c] = a[c];
}

// ---------------- K-split embedding GEMM: hpart[ks] = x[:,ksel] @ W[ksel,:] ----------------
__global__ __launch_bounds__(256) void k_emb_part(const float* __restrict__ x,
                                                  const float* __restrict__ W,   // [2000][128]
                                                  float* __restrict__ hpart) {
    __shared__ float As[64 * 17];
    __shared__ float Bs[16 * 64];
    int tid = threadIdx.x;
    int b = blockIdx.x;
    int ks = b & 3, nt = (b >> 2) & 1, mt = b >> 3;
    int row0 = mt * 64, n0 = nt * 64;
    int kt0 = ks * 32, kt1 = min(125, kt0 + 32);
    int tx = tid & 15, ty = tid >> 4;
    float acc[4][4] = {};
    int ar = tid >> 2, ac = (tid & 3) * 4;
    int bkr = tid >> 4, bc = (tid & 15) * 4;
    for (int kt = kt0; kt < kt1; ++kt) {
        int k0 = kt * 16;
        if (row0 + ar < N_NODES) {
            f32x4 av = *(const f32x4*)(x + (long)(row0 + ar) * KEMB + k0 + ac);
#pragma unroll
            for (int j = 0; j < 4; ++j) As[ar * 17 + ac + j] = av[j];
        } else {
#pragma unroll
            for (int j = 0; j < 4; ++j) As[ar * 17 + ac + j] = 0.f;
        }
        *(f32x4*)(Bs + bkr * 64 + bc) = *(const f32x4*)(W + (long)(k0 + bkr) * EMB + n0 + bc);
        __syncthreads();
#pragma unroll 1
        for (int kk = 0; kk < 16; ++kk) {
            float a[4];
#pragma unroll
            for (int i = 0; i < 4; ++i) a[i] = As[(ty * 4 + i) * 17 + kk];
            f32x4 bv = *(const f32x4*)(Bs + kk * 64 + tx * 4);
#pragma unroll
            for (int i = 0; i < 4; ++i)
#pragma unroll
                for (int j = 0; j < 4; ++j) acc[i][j] += a[i] * bv[j];
        }
        __syncthreads();
    }
    float* hp = hpart + (size_t)ks * N_NODES * EMB;
#pragma unroll
    for (int i = 0; i < 4; ++i) {
        int row = row0 + ty * 4 + i;
        if (row >= N_NODES) continue;
        f32x4 o;
#pragma unroll
        for (int j = 0; j < 4; ++j) o[j] = acc[i][j];
        *(f32x4*)(hp + (long)row * EMB + n0 + tx * 4) = o;
    }
}

// h = sum_{ks} hpart[ks] + bias  (deterministic)
__global__ __launch_bounds__(256) void k_emb_reduce(const float* __restrict__ hpart,
                                                    const float* __restrict__ bias,
                                                    float* __restrict__ h) {
    long i = (long)blockIdx.x * 256 + threadIdx.x;
    long p = i * 4;
    int c = (int)(p & 127);
    f32x4 a0 = *(const f32x4*)(hpart + p);
    f32x4 a1 = *(const f32x4*)(hpart + (size_t)N_NODES * EMB + p);
    f32x4 a2 = *(const f32x4*)(hpart + 2 * (size_t)N_NODES * EMB + p);
    f32x4 a3 = *(const f32x4*)(hpart + 3 * (size_t)N_NODES * EMB + p);
    f32x4 bb = *(const f32x4*)(bias + c);
    f32x4 o;
#pragma unroll
    for (int j = 0; j < 4; ++j) o[j] = (a0[j] + a1[j]) + (a2[j] + a3[j]) + bb[j];
    *(f32x4*)(h + p) = o;
}

// ---------------- fallback monolithic embedding GEMM ----------------
__global__ __launch_bounds__(256) void k_emb_f32(const float* __restrict__ x,
                                                 const float* __restrict__ W,
                                                 const float* __restrict__ bias,
                                                 float* __restrict__ h) {
    __shared__ float As[64 * 17];
    __shared__ float Bs[16 * 64];
    int tid = threadIdx.x;
    int mt = blockIdx.x >> 1, nt = blockIdx.x & 1;
    int row0 = mt * 64, n0 = nt * 64;
    int tx = tid & 15, ty = tid >> 4;
    float acc[4][4] = {};
    int ar = tid >> 2, ac = (tid & 3) * 4;
    int bkr = tid >> 4, bc = (tid & 15) * 4;
    for (int kt = 0; kt < 125; ++kt) {
        int k0 = kt * 16;
        if (row0 + ar < N_NODES) {
            f32x4 av = *(const f32x4*)(x + (long)(row0 + ar) * KEMB + k0 + ac);
#pragma unroll
            for (int j = 0; j < 4; ++j) As[ar * 17 + ac + j] = av[j];
        } else {
#pragma unroll
            for (int j = 0; j < 4; ++j) As[ar * 17 + ac + j] = 0.f;
        }
        *(f32x4*)(Bs + bkr * 64 + bc) = *(const f32x4*)(W + (long)(k0 + bkr) * EMB + n0 + bc);
        __syncthreads();
#pragma unroll 1
        for (int kk = 0; kk < 16; ++kk) {
            float a[4];
#pragma unroll
            for (int i = 0; i < 4; ++i) a[i] = As[(ty * 4 + i) * 17 + kk];
            f32x4 bv = *(const f32x4*)(Bs + kk * 64 + tx * 4);
#pragma unroll
            for (int i = 0; i < 4; ++i)
#pragma unroll
                for (int j = 0; j < 4; ++j) acc[i][j] += a[i] * bv[j];
        }
        __syncthreads();
    }
#pragma unroll
    for (int i = 0; i < 4; ++i) {
        int row = row0 + ty * 4 + i;
        if (row >= N_NODES) continue;
        f32x4 o;
#pragma unroll
        for (int j = 0; j < 4; ++j) o[j] = acc[i][j] + bias[n0 + tx * 4 + j];
        *(f32x4*)(h + (long)row * EMB + n0 + tx * 4) = o;
    }
}

// ---------------- FUSED message + segment-sum aggregate ----------------
// Block = 128 sorted edges (2 waves). Phase 1: per-thread matvec -> LDS tile.
// Phase 2: dst-sorted runs summed per node; interior nodes plain-store,
// boundary nodes atomicAdd (~2 per block). No mbuf materialization.
__global__ __launch_bounds__(128) void k_msgaggr(const float* __restrict__ h,
                                                 const float* __restrict__ ea_s,
                                                 const int* __restrict__ src_s,
                                                 const int* __restrict__ dst_s,
                                                 const int* __restrict__ row_start,
                                                 const float* __restrict__ mW,   // [160][64]
                                                 const float* __restrict__ mb,   // [64]
                                                 const float* __restrict__ P,    // [2000][64]
                                                 const int* __restrict__ smax,
                                                 float* __restrict__ aggr) {
    __shared__ float lm[MBLK * 68];   // row stride 68 floats (16B-aligned, banks spread)
    __shared__ int sdst[MBLK];
    int tid = threadIdx.x;
    int b0 = blockIdx.x * MBLK;
    int i = b0 + tid;
    int s = src_s[i];
    sdst[tid] = dst_s[i];
    float acc[PD];
#pragma unroll
    for (int o = 0; o < PD; ++o) acc[o] = mb[o];
#pragma unroll 1
    for (int kb = 0; kb < 10; ++kb) {
        float in[16];
        if (kb < 8) {
            f32x4 v0 = *(const f32x4*)(h + (long)s * EMB + kb * 16);
            f32x4 v1 = *(const f32x4*)(h + (long)s * EMB + kb * 16 + 4);
            f32x4 v2 = *(const f32x4*)(h + (long)s * EMB + kb * 16 + 8);
            f32x4 v3 = *(const f32x4*)(h + (long)s * EMB + kb * 16 + 12);
#pragma unroll
            for (int j = 0; j < 4; ++j) { in[j] = v0[j]; in[4+j] = v1[j]; in[8+j] = v2[j]; in[12+j] = v3[j]; }
        } else {
            f32x4 v0 = *(const f32x4*)(ea_s + (long)i * ED + (kb - 8) * 16);
            f32x4 v1 = *(const f32x4*)(ea_s + (long)i * ED + (kb - 8) * 16 + 4);
            f32x4 v2 = *(const f32x4*)(ea_s + (long)i * ED + (kb - 8) * 16 + 8);
            f32x4 v3 = *(const f32x4*)(ea_s + (long)i * ED + (kb - 8) * 16 + 12);
#pragma unroll
            for (int j = 0; j < 4; ++j) { in[j] = v0[j]; in[4+j] = v1[j]; in[8+j] = v2[j]; in[12+j] = v3[j]; }
        }
#pragma unroll 1
        for (int kk = 0; kk < 16; ++kk) {
            const float* wrow = mW + (long)(kb * 16 + kk) * PD;  // lane-uniform -> s_load
            float v = in[kk];
#pragma unroll
            for (int o = 0; o < PD; ++o) acc[o] += v * wrow[o];
        }
    }
    int base = *smax - (NGENES - 1);
    const float* Pe = P + (long)(s - base) * PD;
#pragma unroll
    for (int c = 0; c < 16; ++c) {
        f32x4 v;
#pragma unroll
        for (int j = 0; j < 4; ++j) v[j] = fmaxf(acc[c * 4 + j], 0.f) * Pe[c * 4 + j];
        *(f32x4*)(&lm[tid * 68 + c * 4]) = v;
    }
    __syncthreads();
    // phase 2: per-node segment sums over this block's rows
    int d_lo = sdst[0], d_hi = sdst[MBLK - 1];
    int wv = tid >> 6, lane = tid & 63;
    for (int d = d_lo + wv; d <= d_hi; d += 2) {
        int r0 = row_start[d], r1 = row_start[d + 1];
        int j0 = max(r0, b0), j1 = min(r1, b0 + MBLK);
        if (j0 >= j1) continue;
        float s0 = 0.f, s1 = 0.f;
        int j = j0;
        for (; j + 1 < j1; j += 2) {
            s0 += lm[(j - b0) * 68 + lane];
            s1 += lm[(j + 1 - b0) * 68 + lane];
        }
        if (j < j1) s0 += lm[(j - b0) * 68 + lane];
        float sum = s0 + s1;
        if (r0 >= b0 && r1 <= b0 + MBLK)
            aggr[(long)d * PD + lane] = sum;                      // node fully owned
        else
            unsafeAtomicAdd(&aggr[(long)d * PD + lane], sum);     // boundary node
    }
}

// ---------------- fallback fused message (atomic scatter) ----------------
__global__ __launch_bounds__(256) void k_msg_f32(const float* __restrict__ h,
                                                 const float* __restrict__ ea,
                                                 const int* __restrict__ src,
                                                 const int* __restrict__ dst,
                                                 const float* __restrict__ mW,
                                                 const float* __restrict__ mb,
                                                 const float* __restrict__ P,
                                                 const int* __restrict__ smax,
                                                 float* __restrict__ aggr) {
    int e = blockIdx.x * 256 + threadIdx.x;
    int s = src[e], d = dst[e];
    float acc[PD];
#pragma unroll
    for (int o = 0; o < PD; ++o) acc[o] = mb[o];
#pragma unroll 1
    for (int kb = 0; kb < 10; ++kb) {
        float in[16];
        if (kb < 8) {
            f32x4 v0 = *(const f32x4*)(h + (long)s * EMB + kb * 16);
            f32x4 v1 = *(const f32x4*)(h + (long)s * EMB + kb * 16 + 4);
            f32x4 v2 = *(const f32x4*)(h + (long)s * EMB + kb * 16 + 8);
            f32x4 v3 = *(const f32x4*)(h + (long)s * EMB + kb * 16 + 12);
#pragma unroll
            for (int j = 0; j < 4; ++j) { in[j] = v0[j]; in[4+j] = v1[j]; in[8+j] = v2[j]; in[12+j] = v3[j]; }
        } else {
            f32x4 v0 = *(const f32x4*)(ea + (long)e * ED + (kb - 8) * 16);
            f32x4 v1 = *(const f32x4*)(ea + (long)e * ED + (kb - 8) * 16 + 4);
            f32x4 v2 = *(const f32x4*)(ea + (long)e * ED + (kb - 8) * 16 + 8);
            f32x4 v3 = *(const f32x4*)(ea + (long)e * ED + (kb - 8) * 16 + 12);
#pragma unroll
            for (int j = 0; j < 4; ++j) { in[j] = v0[j]; in[4+j] = v1[j]; in[8+j] = v2[j]; in[12+j] = v3[j]; }
        }
#pragma unroll 1
        for (int kk = 0; kk < 16; ++kk) {
            const float* wrow = mW + (long)(kb * 16 + kk) * PD;
            float v = in[kk];
#pragma unroll
            for (int o = 0; o < PD; ++o) acc[o] += v * wrow[o];
        }
    }
    int base = *smax - (NGENES - 1);
    const float* Pe = P + (long)(s - base) * PD;
    float* arow = aggr + (long)d * PD;
#pragma unroll
    for (int o = 0; o < PD; ++o) {
        float v = fmaxf(acc[o], 0.f) * Pe[o];
        unsafeAtomicAdd(arow + o, v);
    }
}

// ---------------- update f32 (in-place h): h = relu(cat(aggr,h) @ W + b) ----------------
__global__ __launch_bounds__(512) void k_upd_f32(const float* __restrict__ aggr,
                                                 float* __restrict__ h,
                                                 const float* __restrict__ uW,  // [192][128]
                                                 const float* __restrict__ ub)  // [128]
{
    __shared__ float lds[64 * 193];
    int tid = threadIdx.x;
    int n0 = blockIdx.x * 64;
    for (int i = tid; i < 64 * 64; i += 512) {
        int nl = i >> 6, k = i & 63;
        lds[nl * 193 + k] = (n0 + nl < N_NODES) ? aggr[(long)(n0 + nl) * PD + k] : 0.f;
    }
    for (int i = tid; i < 64 * 128; i += 512) {
        int nl = i >> 7, k = i & 127;
        lds[nl * 193 + 64 + k] = (n0 + nl < N_NODES) ? h[(long)(n0 + nl) * EMB + k] : 0.f;
    }
    __syncthreads();
    int wv = tid >> 6, l = tid & 63;
    int o0 = wv * 16;
    int n = n0 + l;
    float acc[16];
#pragma unroll
    for (int o = 0; o < 16; ++o) acc[o] = ub[o0 + o];
#pragma unroll 4
    for (int k = 0; k < 192; ++k) {
        float v = lds[l * 193 + k];
        const float* wrow = uW + (long)k * EMB + o0;
#pragma unroll
        for (int o = 0; o < 16; ++o) acc[o] += v * wrow[o];
    }
    if (n < N_NODES) {
#pragma unroll
        for (int c = 0; c < 4; ++c) {
            f32x4 v;
#pragma unroll
            for (int j = 0; j < 4; ++j) v[j] = fmaxf(acc[c * 4 + j], 0.f);
            *(f32x4*)(h + (long)n * EMB + o0 + c * 4) = v;
        }
    }
}

// ---------------- node head + per-node edge projections ----------------
// out = h @ W_node + b; pn1 = h . Wep[0:128]; pn2 = h . Wep[128:256]
__global__ __launch_bounds__(256) void k_node_pn(const float* __restrict__ h,
                                                 const float* __restrict__ W,  // [128][16]
                                                 const float* __restrict__ b,
                                                 const float* __restrict__ Wep, // [288]
                                                 float* __restrict__ out,
                                                 float* __restrict__ pn1,
                                                 float* __restrict__ pn2) {
    int n = blockIdx.x * 256 + threadIdx.x;
    if (n >= N_NODES) return;
    float acc[OUTD];
#pragma unroll
    for (int o = 0; o < OUTD; ++o) acc[o] = b[o];
    float p1a = 0.f, p1b = 0.f, p2a = 0.f, p2b = 0.f;
#pragma unroll 1
    for (int kb = 0; kb < 32; ++kb) {
        f32x4 hv = *(const f32x4*)(h + (long)n * EMB + kb * 4);
#pragma unroll
        for (int j = 0; j < 4; ++j) {
            const float* wrow = W + (long)(kb * 4 + j) * OUTD;
#pragma unroll
            for (int o = 0; o < OUTD; ++o) acc[o] += hv[j] * wrow[o];
        }
        p1a += hv[0] * Wep[kb * 4 + 0] + hv[1] * Wep[kb * 4 + 1];
        p1b += hv[2] * Wep[kb * 4 + 2] + hv[3] * Wep[kb * 4 + 3];
        p2a += hv[0] * Wep[128 + kb * 4 + 0] + hv[1] * Wep[128 + kb * 4 + 1];
        p2b += hv[2] * Wep[128 + kb * 4 + 2] + hv[3] * Wep[128 + kb * 4 + 3];
    }
#pragma unroll
    for (int c = 0; c < 4; ++c) {
        f32x4 v;
#pragma unroll
        for (int j = 0; j < 4; ++j) v[j] = acc[c * 4 + j];
        *(f32x4*)(out + (long)n * OUTD + c * 4) = v;
    }
    pn1[n] = p1a + p1b;
    pn2[n] = p2a + p2b;
}

// ---------------- fallback node head ----------------
__global__ __launch_bounds__(256) void k_node_f32(const float* __restrict__ h,
                                                  const float* __restrict__ W,
                                                  const float* __restrict__ b,
                                                  float* __restrict__ out) {
    int n = blockIdx.x * 256 + threadIdx.x;
    if (n >= N_NODES) return;
    float acc[OUTD];
#pragma unroll
    for (int o = 0; o < OUTD; ++o) acc[o] = b[o];
#pragma unroll 1
    for (int kb = 0; kb < 32; ++kb) {
        f32x4 hv = *(const f32x4*)(h + (long)n * EMB + kb * 4);
#pragma unroll
        for (int j = 0; j < 4; ++j) {
            const float* wrow = W + (long)(kb * 4 + j) * OUTD;
#pragma unroll
            for (int o = 0; o < OUTD; ++o) acc[o] += hv[j] * wrow[o];
        }
    }
#pragma unroll
    for (int c = 0; c < 4; ++c) {
        f32x4 v;
#pragma unroll
        for (int j = 0; j < 4; ++j) v[j] = acc[c * 4 + j];
        *(f32x4*)(out + (long)n * OUTD + c * 4) = v;
    }
}

// ---------------- edge head via precomputed node projections ----------------
__global__ __launch_bounds__(256) void k_edge2(const float* __restrict__ ea,
                                               const int* __restrict__ src,
                                               const int* __restrict__ dstv,
                                               const float* __restrict__ pn1,
                                               const float* __restrict__ pn2,
                                               const float* __restrict__ Wep, // [288]
                                               const float* __restrict__ bep,
                                               float* __restrict__ out) {
    int e = blockIdx.x * 256 + threadIdx.x;
    float a0 = bep[0] + pn1[src[e]] + pn2[dstv[e]];
    float a1 = 0.f, a2 = 0.f, a3 = 0.f;
#pragma unroll
    for (int kb = 0; kb < 8; ++kb) {
        f32x4 av = *(const f32x4*)(ea + (long)e * ED + kb * 4);
        a0 += av[0] * Wep[256 + kb * 4 + 0];
        a1 += av[1] * Wep[256 + kb * 4 + 1];
        a2 += av[2] * Wep[256 + kb * 4 + 2];
        a3 += av[3] * Wep[256 + kb * 4 + 3];
    }
    out[e] = (a0 + a1) + (a2 + a3);
}

// ---------------- fallback edge head ----------------
__global__ __launch_bounds__(256) void k_edge_f32(const float* __restrict__ h,
                                                  const float* __restrict__ ea,
                                                  const int* __restrict__ src,
                                                  const int* __restrict__ dst,
                                                  const float* __restrict__ Wep,
                                                  const float* __restrict__ bep,
                                                  float* __restrict__ out) {
    int e = blockIdx.x * 256 + threadIdx.x;
    int s = src[e], d = dst[e];
    float a0 = bep[0], a1 = 0.f, a2 = 0.f, a3 = 0.f;
#pragma unroll 1
    for (int kb = 0; kb < 32; ++kb) {
        f32x4 hv = *(const f32x4*)(h + (long)s * EMB + kb * 4);
        a0 += hv[0] * Wep[kb * 4 + 0];
        a1 += hv[1] * Wep[kb * 4 + 1];
        a2 += hv[2] * Wep[kb * 4 + 2];
        a3 += hv[3] * Wep[kb * 4 + 3];
    }
#pragma unroll 1
    for (int kb = 0; kb < 32; ++kb) {
        f32x4 hv = *(const f32x4*)(h + (long)d * EMB + kb * 4);
        a0 += hv[0] * Wep[128 + kb * 4 + 0];
        a1 += hv[1] * Wep[128 + kb * 4 + 1];
        a2 += hv[2] * Wep[128 + kb * 4 + 2];
        a3 += hv[3] * Wep[128 + kb * 4 + 3];
    }
#pragma unroll 1
    for (int kb = 0; kb < 8; ++kb) {
        f32x4 av = *(const f32x4*)(ea + (long)e * ED + kb * 4);
        a0 += av[0] * Wep[256 + kb * 4 + 0];
        a1 += av[1] * Wep[256 + kb * 4 + 1];
        a2 += av[2] * Wep[256 + kb * 4 + 2];
        a3 += av[3] * Wep[256 + kb * 4 + 3];
    }
    out[e] = (a0 + a1) + (a2 + a3);
}

extern "C" void kernel_launch(void* const* d_in, const int* in_sizes, int n_in,
                              void* d_out, int out_size, void* d_ws, size_t ws_size,
                              hipStream_t stream) {
    const float* x      = (const float*)d_in[0];
    const float* ea     = (const float*)d_in[1];
    const int*   eidx   = (const int*)d_in[2];
    const float* W_emb  = (const float*)d_in[3];
    const float* b_emb  = (const float*)d_in[4];
    const float* msg_W  = (const float*)d_in[5];
    const float* msg_b  = (const float*)d_in[6];
    const float* upd_W  = (const float*)d_in[7];
    const float* upd_b  = (const float*)d_in[8];
    const float* W_node = (const float*)d_in[9];
    const float* b_node = (const float*)d_in[10];
    const float* W_ep   = (const float*)d_in[11];
    const float* b_ep   = (const float*)d_in[12];
    const float* P      = (const float*)d_in[13];
    float* out = (float*)d_out;

    const int* src = eidx;
    const int* dst = eidx + NEDGE;

    // ---- base workspace ----
    size_t off = 0;
    char* w = (char*)d_ws;
    float* h    = (float*)(w + off); off += (size_t)N_NODES * EMB * 4;   // 10.24 MB
    float* aggr = (float*)(w + off); off += (size_t)N_NODES * PD * 4;    // 5.12 MB
    int*   smax = (int*)(w + off);   off += 16;
    if (ws_size < off) return;

    // ---- extended (sorted, fused) layout ----
    size_t off2 = off;
    int* cnt       = (int*)(w + off2); off2 += (size_t)N_NODES * 4;
    int* row_start = (int*)(w + off2); off2 += ((size_t)(N_NODES + 1) * 4 + 15) & ~15ull;
    int* cursor    = (int*)(w + off2); off2 += (size_t)N_NODES * 4;
    int* perm      = (int*)(w + off2); off2 += (size_t)NEDGE * 4;          // 2.56 MB
    int* src_s     = (int*)(w + off2); off2 += (size_t)NEDGE * 4;          // 2.56 MB
    int* dst_s     = (int*)(w + off2); off2 += (size_t)NEDGE * 4;          // 2.56 MB
    float* pn1     = (float*)(w + off2); off2 += (size_t)N_NODES * 4;
    float* pn2     = (float*)(w + off2); off2 += (size_t)N_NODES * 4;
    float* ea_s    = (float*)(w + off2); off2 += (size_t)NEDGE * ED * 4;   // 81.92 MB
    float* hpart   = (float*)(w + off2); off2 += 4 * (size_t)N_NODES * EMB * 4; // 40.96 MB
    const bool fast = (ws_size >= off2);   // ~146.5 MB total

    hipMemsetAsync(smax, 0, 4, stream);

    if (fast) {
        // CSR build + sorted gather (dst constant across both layers)
        hipMemsetAsync(cnt, 0, (size_t)N_NODES * 4, stream);
        k_prep<<<NEDGE / 256, 256, 0, stream>>>(src, dst, smax, cnt);
        k_scan<<<1, 1024, 0, stream>>>(cnt, row_start, cursor);
        k_scatter<<<NEDGE / 256, 256, 0, stream>>>(dst, cursor, perm);
        k_gather<<<NEDGE / 256, 256, 0, stream>>>(ea, src, dst, perm, ea_s, src_s, dst_s);

        // K-split embedding GEMM + reduce
        k_emb_part<<<313 * 8, 256, 0, stream>>>(x, W_emb, hpart);
        k_emb_reduce<<<2500, 256, 0, stream>>>(hpart, b_emb, h);

        // layer 0
        hipMemsetAsync(aggr, 0, (size_t)N_NODES * PD * 4, stream);
        k_msgaggr<<<NEDGE / MBLK, MBLK, 0, stream>>>(h, ea_s, src_s, dst_s, row_start,
                                                     msg_W, msg_b, P, smax, aggr);
        k_upd_f32<<<313, 512, 0, stream>>>(aggr, h, upd_W, upd_b);
        // layer 1
        hipMemsetAsync(aggr, 0, (size_t)N_NODES * PD * 4, stream);
        k_msgaggr<<<NEDGE / MBLK, MBLK, 0, stream>>>(h, ea_s, src_s, dst_s, row_start,
                                                     msg_W + 160 * PD, msg_b + PD, P, smax, aggr);
        k_upd_f32<<<313, 512, 0, stream>>>(aggr, h, upd_W + 192 * EMB, upd_b + EMB);

        // heads: node + per-node edge projections, then streaming edge head
        k_node_pn<<<(N_NODES + 255) / 256, 256, 0, stream>>>(h, W_node, b_node, W_ep,
                                                             out, pn1, pn2);
        k_edge2<<<NEDGE / 256, 256, 0, stream>>>(ea, src, dst, pn1, pn2, W_ep, b_ep,
                                                 out + (size_t)N_NODES * OUTD);
    } else {
        // fallback: atomic scatter path
        k_srcmax<<<NEDGE / 256, 256, 0, stream>>>(src, smax);
        k_emb_f32<<<313 * 2, 256, 0, stream>>>(x, W_emb, b_emb, h);
        hipMemsetAsync(aggr, 0, (size_t)N_NODES * PD * 4, stream);
        k_msg_f32<<<NEDGE / 256, 256, 0, stream>>>(h, ea, src, dst, msg_W, msg_b, P, smax, aggr);
        k_upd_f32<<<313, 512, 0, stream>>>(aggr, h, upd_W, upd_b);
        hipMemsetAsync(aggr, 0, (size_t)N_NODES * PD * 4, stream);
        k_msg_f32<<<NEDGE / 256, 256, 0, stream>>>(h, ea, src, dst,
                                                   msg_W + 160 * PD, msg_b + PD, P, smax, aggr);
        k_upd_f32<<<313, 512, 0, stream>>>(aggr, h, upd_W + 192 * EMB, upd_b + EMB);
        k_node_f32<<<(N_NODES + 255) / 256, 256, 0, stream>>>(h, W_node, b_node, out);
        k_edge_f32<<<NEDGE / 256, 256, 0, stream>>>(h, ea, src, dst, W_ep, b_ep,
                                                    out + (size_t)N_NODES * OUTD);
    }
}

// Round 5
// 1215.387 us; speedup vs baseline: 4.4412x; 1.1194x over previous
//
#include <hip/hip_runtime.h>
#include <hip/hip_bf16.h>

typedef float f32x4 __attribute__((ext_vector_type(4)));

#define N_NODES 20000
#define NGENES  2000
#define NEDGE   640000
#define EMB     128
#define ED      32
#define PD      64
#define OUTD    16
#define KEMB    2000

// ---------------- fused: max(src) + dst histogram ----------------
__global__ __launch_bounds__(256) void k_prep(const int* __restrict__ src,
                                              const int* __restrict__ dst,
                                              int* __restrict__ smax,
                                              int* __restrict__ cnt) {
    __shared__ int sm[256];
    int i = blockIdx.x * 256 + threadIdx.x;
    int s = src[i];
    atomicAdd(&cnt[dst[i]], 1);
    sm[threadIdx.x] = s;
    __syncthreads();
    for (int st = 128; st > 0; st >>= 1) {
        if (threadIdx.x < st) sm[threadIdx.x] = max(sm[threadIdx.x], sm[threadIdx.x + st]);
        __syncthreads();
    }
    if (threadIdx.x == 0) atomicMax(smax, sm[0]);
}

// ---------------- fallback srcmax ----------------
__global__ __launch_bounds__(256) void k_srcmax(const int* __restrict__ src,
                                                int* __restrict__ out) {
    __shared__ int sm[256];
    int i = blockIdx.x * 256 + threadIdx.x;
    sm[threadIdx.x] = (i < NEDGE) ? src[i] : 0;
    __syncthreads();
    for (int s = 128; s > 0; s >>= 1) {
        if (threadIdx.x < s) sm[threadIdx.x] = max(sm[threadIdx.x], sm[threadIdx.x + s]);
        __syncthreads();
    }
    if (threadIdx.x == 0) atomicMax(out, sm[0]);
}

// single-block exclusive scan over 20000 bins -> row_start[0..N], cursor[i]=row_start[i]
__global__ __launch_bounds__(1024) void k_scan(const int* __restrict__ cnt,
                                               int* __restrict__ row_start,
                                               int* __restrict__ cursor) {
    __shared__ int a[1024], b[1024];
    __shared__ int carry_s;
    int tid = threadIdx.x;
    if (tid == 0) carry_s = 0;
    __syncthreads();
    for (int chunk = 0; chunk < (N_NODES + 1023) / 1024; ++chunk) {
        int i = chunk * 1024 + tid;
        int v = (i < N_NODES) ? cnt[i] : 0;
        a[tid] = v;
        __syncthreads();
        int* s_ = a; int* d_ = b;
        for (int off = 1; off < 1024; off <<= 1) {
            int val = s_[tid];
            if (tid >= off) val += s_[tid - off];
            d_[tid] = val;
            __syncthreads();
            int* t = s_; s_ = d_; d_ = t;
        }
        int incl = s_[tid];
        int carry = carry_s;
        if (i < N_NODES) {
            row_start[i + 1] = carry + incl;
            cursor[i] = carry + incl - v;
        }
        __syncthreads();
        if (tid == 1023) carry_s = carry + incl;
        __syncthreads();
    }
    if (tid == 0) row_start[0] = 0;
}

__global__ __launch_bounds__(256) void k_scatter(const int* __restrict__ dst,
                                                 int* __restrict__ cursor,
                                                 int* __restrict__ perm) {
    int e = blockIdx.x * 256 + threadIdx.x;
    int pos = atomicAdd(&cursor[dst[e]], 1);
    perm[pos] = e;
}

// ---------------- gather edge data into sorted order (once) ----------------
__global__ __launch_bounds__(256) void k_gather(const float* __restrict__ ea,
                                                const int* __restrict__ src,
                                                const int* __restrict__ perm,
                                                float* __restrict__ ea_s,
                                                int* __restrict__ src_s) {
    int i = blockIdx.x * 256 + threadIdx.x;
    int e = perm[i];
    src_s[i] = src[e];
    const f32x4* a = (const f32x4*)(ea + (long)e * ED);
    f32x4* o = (f32x4*)(ea_s + (long)i * ED);
#pragma unroll
    for (int c = 0; c < 8; ++c) o[c] = a[c];
}

// ---------------- K-split embedding GEMM: hpart[ks] = x[:,ksel] @ W[ksel,:] ----------------
__global__ __launch_bounds__(256) void k_emb_part(const float* __restrict__ x,
                                                  const float* __restrict__ W,   // [2000][128]
                                                  float* __restrict__ hpart) {
    __shared__ float As[64 * 17];
    __shared__ float Bs[16 * 64];
    int tid = threadIdx.x;
    int b = blockIdx.x;
    int ks = b & 3, nt = (b >> 2) & 1, mt = b >> 3;
    int row0 = mt * 64, n0 = nt * 64;
    int kt0 = ks * 32, kt1 = min(125, kt0 + 32);
    int tx = tid & 15, ty = tid >> 4;
    float acc[4][4] = {};
    int ar = tid >> 2, ac = (tid & 3) * 4;
    int bkr = tid >> 4, bc = (tid & 15) * 4;
    for (int kt = kt0; kt < kt1; ++kt) {
        int k0 = kt * 16;
        if (row0 + ar < N_NODES) {
            f32x4 av = *(const f32x4*)(x + (long)(row0 + ar) * KEMB + k0 + ac);
#pragma unroll
            for (int j = 0; j < 4; ++j) As[ar * 17 + ac + j] = av[j];
        } else {
#pragma unroll
            for (int j = 0; j < 4; ++j) As[ar * 17 + ac + j] = 0.f;
        }
        *(f32x4*)(Bs + bkr * 64 + bc) = *(const f32x4*)(W + (long)(k0 + bkr) * EMB + n0 + bc);
        __syncthreads();
#pragma unroll 1
        for (int kk = 0; kk < 16; ++kk) {
            float a[4];
#pragma unroll
            for (int i = 0; i < 4; ++i) a[i] = As[(ty * 4 + i) * 17 + kk];
            f32x4 bv = *(const f32x4*)(Bs + kk * 64 + tx * 4);
#pragma unroll
            for (int i = 0; i < 4; ++i)
#pragma unroll
                for (int j = 0; j < 4; ++j) acc[i][j] += a[i] * bv[j];
        }
        __syncthreads();
    }
    float* hp = hpart + (size_t)ks * N_NODES * EMB;
#pragma unroll
    for (int i = 0; i < 4; ++i) {
        int row = row0 + ty * 4 + i;
        if (row >= N_NODES) continue;
        f32x4 o;
#pragma unroll
        for (int j = 0; j < 4; ++j) o[j] = acc[i][j];
        *(f32x4*)(hp + (long)row * EMB + n0 + tx * 4) = o;
    }
}

// h = sum_{ks} hpart[ks] + bias  (deterministic)
__global__ __launch_bounds__(256) void k_emb_reduce(const float* __restrict__ hpart,
                                                    const float* __restrict__ bias,
                                                    float* __restrict__ h) {
    long i = (long)blockIdx.x * 256 + threadIdx.x;
    long p = i * 4;
    int c = (int)(p & 127);
    f32x4 a0 = *(const f32x4*)(hpart + p);
    f32x4 a1 = *(const f32x4*)(hpart + (size_t)N_NODES * EMB + p);
    f32x4 a2 = *(const f32x4*)(hpart + 2 * (size_t)N_NODES * EMB + p);
    f32x4 a3 = *(const f32x4*)(hpart + 3 * (size_t)N_NODES * EMB + p);
    f32x4 bb = *(const f32x4*)(bias + c);
    f32x4 o;
#pragma unroll
    for (int j = 0; j < 4; ++j) o[j] = (a0[j] + a1[j]) + (a2[j] + a3[j]) + bb[j];
    *(f32x4*)(h + p) = o;
}

// ---------------- fallback monolithic embedding GEMM ----------------
__global__ __launch_bounds__(256) void k_emb_f32(const float* __restrict__ x,
                                                 const float* __restrict__ W,
                                                 const float* __restrict__ bias,
                                                 float* __restrict__ h) {
    __shared__ float As[64 * 17];
    __shared__ float Bs[16 * 64];
    int tid = threadIdx.x;
    int mt = blockIdx.x >> 1, nt = blockIdx.x & 1;
    int row0 = mt * 64, n0 = nt * 64;
    int tx = tid & 15, ty = tid >> 4;
    float acc[4][4] = {};
    int ar = tid >> 2, ac = (tid & 3) * 4;
    int bkr = tid >> 4, bc = (tid & 15) * 4;
    for (int kt = 0; kt < 125; ++kt) {
        int k0 = kt * 16;
        if (row0 + ar < N_NODES) {
            f32x4 av = *(const f32x4*)(x + (long)(row0 + ar) * KEMB + k0 + ac);
#pragma unroll
            for (int j = 0; j < 4; ++j) As[ar * 17 + ac + j] = av[j];
        } else {
#pragma unroll
            for (int j = 0; j < 4; ++j) As[ar * 17 + ac + j] = 0.f;
        }
        *(f32x4*)(Bs + bkr * 64 + bc) = *(const f32x4*)(W + (long)(k0 + bkr) * EMB + n0 + bc);
        __syncthreads();
#pragma unroll 1
        for (int kk = 0; kk < 16; ++kk) {
            float a[4];
#pragma unroll
            for (int i = 0; i < 4; ++i) a[i] = As[(ty * 4 + i) * 17 + kk];
            f32x4 bv = *(const f32x4*)(Bs + kk * 64 + tx * 4);
#pragma unroll
            for (int i = 0; i < 4; ++i)
#pragma unroll
                for (int j = 0; j < 4; ++j) acc[i][j] += a[i] * bv[j];
        }
        __syncthreads();
    }
#pragma unroll
    for (int i = 0; i < 4; ++i) {
        int row = row0 + ty * 4 + i;
        if (row >= N_NODES) continue;
        f32x4 o;
#pragma unroll
        for (int j = 0; j < 4; ++j) o[j] = acc[i][j] + bias[n0 + tx * 4 + j];
        *(f32x4*)(h + (long)row * EMB + n0 + tx * 4) = o;
    }
}

// ---------------- per-gene transform: G[g] = h[base+g] @ W_h + mb ----------------
// W_h = mW rows 0..127 (contiguous first 8192 floats). 4 genes/block (wave each).
__global__ __launch_bounds__(256) void k_gene(const float* __restrict__ h,
                                              const float* __restrict__ mW,   // [160][64]
                                              const float* __restrict__ mb,   // [64]
                                              const int* __restrict__ smax,
                                              float* __restrict__ G) {
    __shared__ float Ws[128 * 64];
    __shared__ float hs[4][128];
    int tid = threadIdx.x;
    for (int i = tid; i < 2048; i += 256)
        *(f32x4*)(Ws + i * 4) = *(const f32x4*)(mW + i * 4);
    int base = *smax - (NGENES - 1);
    int g0 = blockIdx.x * 4;
    for (int i = tid; i < 128; i += 256) {
        int r = i >> 5, c = (i & 31) * 4;
        *(f32x4*)(&hs[r][c]) = *(const f32x4*)(h + (long)(base + g0 + r) * EMB + c);
    }
    __syncthreads();
    int wv = tid >> 6, lane = tid & 63;
    float a0 = mb[lane], a1 = 0.f, a2 = 0.f, a3 = 0.f;
#pragma unroll 8
    for (int k = 0; k < 128; k += 4) {
        a0 += hs[wv][k + 0] * Ws[(k + 0) * 64 + lane];
        a1 += hs[wv][k + 1] * Ws[(k + 1) * 64 + lane];
        a2 += hs[wv][k + 2] * Ws[(k + 2) * 64 + lane];
        a3 += hs[wv][k + 3] * Ws[(k + 3) * 64 + lane];
    }
    G[(long)(g0 + wv) * PD + lane] = (a0 + a1) + (a2 + a3);
}

// ---------------- fused per-node message+aggregate ----------------
// Wave per node (lane = output channel). Per edge: t = G[g] + ea@W_e;
// acc += relu(t)*P[g]. W_e column held in 32 VGPRs. No atomics, no LDS.
__global__ __launch_bounds__(256) void k_fusedagg(const float* __restrict__ G,
                                                  const float* __restrict__ mW,   // [160][64]
                                                  const float* __restrict__ P,    // [2000][64]
                                                  const float* __restrict__ ea_s,
                                                  const int* __restrict__ src_s,
                                                  const int* __restrict__ row_start,
                                                  const int* __restrict__ smax,
                                                  float* __restrict__ aggr) {
    int tid = threadIdx.x;
    int wv = tid >> 6, lane = tid & 63;
    float we[32];
#pragma unroll
    for (int k = 0; k < 32; ++k) we[k] = mW[(long)(128 + k) * PD + lane];
    int base = *smax - (NGENES - 1);
    int n = blockIdx.x * 4 + wv;
    int j0 = row_start[n], j1 = row_start[n + 1];
    float acc = 0.f;
    for (int j = j0; j < j1; ++j) {
        int g = src_s[j] - base;
        const f32x4* er = (const f32x4*)(ea_s + (long)j * ED);
        f32x4 ev[8];
#pragma unroll
        for (int c = 0; c < 8; ++c) ev[c] = er[c];
        float t0 = G[(long)g * PD + lane], t1 = 0.f, t2 = 0.f, t3 = 0.f;
#pragma unroll
        for (int c = 0; c < 8; ++c) {
            t0 += ev[c][0] * we[c * 4 + 0];
            t1 += ev[c][1] * we[c * 4 + 1];
            t2 += ev[c][2] * we[c * 4 + 2];
            t3 += ev[c][3] * we[c * 4 + 3];
        }
        float t = (t0 + t1) + (t2 + t3);
        acc += fmaxf(t, 0.f) * P[(long)g * PD + lane];
    }
    aggr[(long)n * PD + lane] = acc;
}

// ---------------- fallback fused message (atomic scatter) ----------------
__global__ __launch_bounds__(256) void k_msg_f32(const float* __restrict__ h,
                                                 const float* __restrict__ ea,
                                                 const int* __restrict__ src,
                                                 const int* __restrict__ dst,
                                                 const float* __restrict__ mW,
                                                 const float* __restrict__ mb,
                                                 const float* __restrict__ P,
                                                 const int* __restrict__ smax,
                                                 float* __restrict__ aggr) {
    int e = blockIdx.x * 256 + threadIdx.x;
    int s = src[e], d = dst[e];
    float acc[PD];
#pragma unroll
    for (int o = 0; o < PD; ++o) acc[o] = mb[o];
#pragma unroll 1
    for (int kb = 0; kb < 10; ++kb) {
        float in[16];
        if (kb < 8) {
            f32x4 v0 = *(const f32x4*)(h + (long)s * EMB + kb * 16);
            f32x4 v1 = *(const f32x4*)(h + (long)s * EMB + kb * 16 + 4);
            f32x4 v2 = *(const f32x4*)(h + (long)s * EMB + kb * 16 + 8);
            f32x4 v3 = *(const f32x4*)(h + (long)s * EMB + kb * 16 + 12);
#pragma unroll
            for (int j = 0; j < 4; ++j) { in[j] = v0[j]; in[4+j] = v1[j]; in[8+j] = v2[j]; in[12+j] = v3[j]; }
        } else {
            f32x4 v0 = *(const f32x4*)(ea + (long)e * ED + (kb - 8) * 16);
            f32x4 v1 = *(const f32x4*)(ea + (long)e * ED + (kb - 8) * 16 + 4);
            f32x4 v2 = *(const f32x4*)(ea + (long)e * ED + (kb - 8) * 16 + 8);
            f32x4 v3 = *(const f32x4*)(ea + (long)e * ED + (kb - 8) * 16 + 12);
#pragma unroll
            for (int j = 0; j < 4; ++j) { in[j] = v0[j]; in[4+j] = v1[j]; in[8+j] = v2[j]; in[12+j] = v3[j]; }
        }
#pragma unroll 1
        for (int kk = 0; kk < 16; ++kk) {
            const float* wrow = mW + (long)(kb * 16 + kk) * PD;
            float v = in[kk];
#pragma unroll
            for (int o = 0; o < PD; ++o) acc[o] += v * wrow[o];
        }
    }
    int base = *smax - (NGENES - 1);
    const float* Pe = P + (long)(s - base) * PD;
    float* arow = aggr + (long)d * PD;
#pragma unroll
    for (int o = 0; o < PD; ++o) {
        float v = fmaxf(acc[o], 0.f) * Pe[o];
        unsafeAtomicAdd(arow + o, v);
    }
}

// ---------------- update f32 (in-place h): h = relu(cat(aggr,h) @ W + b) ----------------
__global__ __launch_bounds__(512) void k_upd_f32(const float* __restrict__ aggr,
                                                 float* __restrict__ h,
                                                 const float* __restrict__ uW,  // [192][128]
                                                 const float* __restrict__ ub)  // [128]
{
    __shared__ float lds[64 * 193];
    int tid = threadIdx.x;
    int n0 = blockIdx.x * 64;
    for (int i = tid; i < 64 * 64; i += 512) {
        int nl = i >> 6, k = i & 63;
        lds[nl * 193 + k] = (n0 + nl < N_NODES) ? aggr[(long)(n0 + nl) * PD + k] : 0.f;
    }
    for (int i = tid; i < 64 * 128; i += 512) {
        int nl = i >> 7, k = i & 127;
        lds[nl * 193 + 64 + k] = (n0 + nl < N_NODES) ? h[(long)(n0 + nl) * EMB + k] : 0.f;
    }
    __syncthreads();
    int wv = tid >> 6, l = tid & 63;
    int o0 = wv * 16;
    int n = n0 + l;
    float acc[16];
#pragma unroll
    for (int o = 0; o < 16; ++o) acc[o] = ub[o0 + o];
#pragma unroll 4
    for (int k = 0; k < 192; ++k) {
        float v = lds[l * 193 + k];
        const float* wrow = uW + (long)k * EMB + o0;
#pragma unroll
        for (int o = 0; o < 16; ++o) acc[o] += v * wrow[o];
    }
    if (n < N_NODES) {
#pragma unroll
        for (int c = 0; c < 4; ++c) {
            f32x4 v;
#pragma unroll
            for (int j = 0; j < 4; ++j) v[j] = fmaxf(acc[c * 4 + j], 0.f);
            *(f32x4*)(h + (long)n * EMB + o0 + c * 4) = v;
        }
    }
}

// ---------------- node head + per-node edge projections ----------------
__global__ __launch_bounds__(256) void k_node_pn(const float* __restrict__ h,
                                                 const float* __restrict__ W,  // [128][16]
                                                 const float* __restrict__ b,
                                                 const float* __restrict__ Wep, // [288]
                                                 float* __restrict__ out,
                                                 float* __restrict__ pn1,
                                                 float* __restrict__ pn2) {
    int n = blockIdx.x * 256 + threadIdx.x;
    if (n >= N_NODES) return;
    float acc[OUTD];
#pragma unroll
    for (int o = 0; o < OUTD; ++o) acc[o] = b[o];
    float p1a = 0.f, p1b = 0.f, p2a = 0.f, p2b = 0.f;
#pragma unroll 1
    for (int kb = 0; kb < 32; ++kb) {
        f32x4 hv = *(const f32x4*)(h + (long)n * EMB + kb * 4);
#pragma unroll
        for (int j = 0; j < 4; ++j) {
            const float* wrow = W + (long)(kb * 4 + j) * OUTD;
#pragma unroll
            for (int o = 0; o < OUTD; ++o) acc[o] += hv[j] * wrow[o];
        }
        p1a += hv[0] * Wep[kb * 4 + 0] + hv[1] * Wep[kb * 4 + 1];
        p1b += hv[2] * Wep[kb * 4 + 2] + hv[3] * Wep[kb * 4 + 3];
        p2a += hv[0] * Wep[128 + kb * 4 + 0] + hv[1] * Wep[128 + kb * 4 + 1];
        p2b += hv[2] * Wep[128 + kb * 4 + 2] + hv[3] * Wep[128 + kb * 4 + 3];
    }
#pragma unroll
    for (int c = 0; c < 4; ++c) {
        f32x4 v;
#pragma unroll
        for (int j = 0; j < 4; ++j) v[j] = acc[c * 4 + j];
        *(f32x4*)(out + (long)n * OUTD + c * 4) = v;
    }
    pn1[n] = p1a + p1b;
    pn2[n] = p2a + p2b;
}

// ---------------- fallback node head ----------------
__global__ __launch_bounds__(256) void k_node_f32(const float* __restrict__ h,
                                                  const float* __restrict__ W,
                                                  const float* __restrict__ b,
                                                  float* __restrict__ out) {
    int n = blockIdx.x * 256 + threadIdx.x;
    if (n >= N_NODES) return;
    float acc[OUTD];
#pragma unroll
    for (int o = 0; o < OUTD; ++o) acc[o] = b[o];
#pragma unroll 1
    for (int kb = 0; kb < 32; ++kb) {
        f32x4 hv = *(const f32x4*)(h + (long)n * EMB + kb * 4);
#pragma unroll
        for (int j = 0; j < 4; ++j) {
            const float* wrow = W + (long)(kb * 4 + j) * OUTD;
#pragma unroll
            for (int o = 0; o < OUTD; ++o) acc[o] += hv[j] * wrow[o];
        }
    }
#pragma unroll
    for (int c = 0; c < 4; ++c) {
        f32x4 v;
#pragma unroll
        for (int j = 0; j < 4; ++j) v[j] = acc[c * 4 + j];
        *(f32x4*)(out + (long)n * OUTD + c * 4) = v;
    }
}

// ---------------- edge head via precomputed node projections ----------------
__global__ __launch_bounds__(256) void k_edge2(const float* __restrict__ ea,
                                               const int* __restrict__ src,
                                               const int* __restrict__ dstv,
                                               const float* __restrict__ pn1,
                                               const float* __restrict__ pn2,
                                               const float* __restrict__ Wep, // [288]
                                               const float* __restrict__ bep,
                                               float* __restrict__ out) {
    int e = blockIdx.x * 256 + threadIdx.x;
    float a0 = bep[0] + pn1[src[e]] + pn2[dstv[e]];
    float a1 = 0.f, a2 = 0.f, a3 = 0.f;
#pragma unroll
    for (int kb = 0; kb < 8; ++kb) {
        f32x4 av = *(const f32x4*)(ea + (long)e * ED + kb * 4);
        a0 += av[0] * Wep[256 + kb * 4 + 0];
        a1 += av[1] * Wep[256 + kb * 4 + 1];
        a2 += av[2] * Wep[256 + kb * 4 + 2];
        a3 += av[3] * Wep[256 + kb * 4 + 3];
    }
    out[e] = (a0 + a1) + (a2 + a3);
}

// ---------------- fallback edge head ----------------
__global__ __launch_bounds__(256) void k_edge_f32(const float* __restrict__ h,
                                                  const float* __restrict__ ea,
                                                  const int* __restrict__ src,
                                                  const int* __restrict__ dst,
                                                  const float* __restrict__ Wep,
                                                  const float* __restrict__ bep,
                                                  float* __restrict__ out) {
    int e = blockIdx.x * 256 + threadIdx.x;
    int s = src[e], d = dst[e];
    float a0 = bep[0], a1 = 0.f, a2 = 0.f, a3 = 0.f;
#pragma unroll 1
    for (int kb = 0; kb < 32; ++kb) {
        f32x4 hv = *(const f32x4*)(h + (long)s * EMB + kb * 4);
        a0 += hv[0] * Wep[kb * 4 + 0];
        a1 += hv[1] * Wep[kb * 4 + 1];
        a2 += hv[2] * Wep[kb * 4 + 2];
        a3 += hv[3] * Wep[kb * 4 + 3];
    }
#pragma unroll 1
    for (int kb = 0; kb < 32; ++kb) {
        f32x4 hv = *(const f32x4*)(h + (long)d * EMB + kb * 4);
        a0 += hv[0] * Wep[128 + kb * 4 + 0];
        a1 += hv[1] * Wep[128 + kb * 4 + 1];
        a2 += hv[2] * Wep[128 + kb * 4 + 2];
        a3 += hv[3] * Wep[128 + kb * 4 + 3];
    }
#pragma unroll 1
    for (int kb = 0; kb < 8; ++kb) {
        f32x4 av = *(const f32x4*)(ea + (long)e * ED + kb * 4);
        a0 += av[0] * Wep[256 + kb * 4 + 0];
        a1 += av[1] * Wep[256 + kb * 4 + 1];
        a2 += av[2] * Wep[256 + kb * 4 + 2];
        a3 += av[3] * Wep[256 + kb * 4 + 3];
    }
    out[e] = (a0 + a1) + (a2 + a3);
}

extern "C" void kernel_launch(void* const* d_in, const int* in_sizes, int n_in,
                              void* d_out, int out_size, void* d_ws, size_t ws_size,
                              hipStream_t stream) {
    const float* x      = (const float*)d_in[0];
    const float* ea     = (const float*)d_in[1];
    const int*   eidx   = (const int*)d_in[2];
    const float* W_emb  = (const float*)d_in[3];
    const float* b_emb  = (const float*)d_in[4];
    const float* msg_W  = (const float*)d_in[5];
    const float* msg_b  = (const float*)d_in[6];
    const float* upd_W  = (const float*)d_in[7];
    const float* upd_b  = (const float*)d_in[8];
    const float* W_node = (const float*)d_in[9];
    const float* b_node = (const float*)d_in[10];
    const float* W_ep   = (const float*)d_in[11];
    const float* b_ep   = (const float*)d_in[12];
    const float* P      = (const float*)d_in[13];
    float* out = (float*)d_out;

    const int* src = eidx;
    const int* dst = eidx + NEDGE;

    // ---- base workspace ----
    size_t off = 0;
    char* w = (char*)d_ws;
    float* h    = (float*)(w + off); off += (size_t)N_NODES * EMB * 4;   // 10.24 MB
    float* aggr = (float*)(w + off); off += (size_t)N_NODES * PD * 4;    // 5.12 MB
    int*   smax = (int*)(w + off);   off += 16;
    if (ws_size < off) return;

    // ---- extended (sorted, fused) layout ----
    size_t off2 = off;
    int* cnt       = (int*)(w + off2); off2 += (size_t)N_NODES * 4;
    int* row_start = (int*)(w + off2); off2 += ((size_t)(N_NODES + 1) * 4 + 15) & ~15ull;
    int* cursor    = (int*)(w + off2); off2 += (size_t)N_NODES * 4;
    int* perm      = (int*)(w + off2); off2 += (size_t)NEDGE * 4;          // 2.56 MB
    int* src_s     = (int*)(w + off2); off2 += (size_t)NEDGE * 4;          // 2.56 MB
    float* pn1     = (float*)(w + off2); off2 += (size_t)N_NODES * 4;
    float* pn2     = (float*)(w + off2); off2 += (size_t)N_NODES * 4;
    float* G       = (float*)(w + off2); off2 += (size_t)NGENES * PD * 4;  // 0.51 MB
    float* ea_s    = (float*)(w + off2); off2 += (size_t)NEDGE * ED * 4;   // 81.92 MB
    float* hpart   = (float*)(w + off2); off2 += 4 * (size_t)N_NODES * EMB * 4; // 40.96 MB
    const bool fast = (ws_size >= off2);   // ~144 MB total

    hipMemsetAsync(smax, 0, 4, stream);

    if (fast) {
        // CSR build + sorted gather (dst constant across both layers)
        hipMemsetAsync(cnt, 0, (size_t)N_NODES * 4, stream);
        k_prep<<<NEDGE / 256, 256, 0, stream>>>(src, dst, smax, cnt);
        k_scan<<<1, 1024, 0, stream>>>(cnt, row_start, cursor);
        k_scatter<<<NEDGE / 256, 256, 0, stream>>>(dst, cursor, perm);
        k_gather<<<NEDGE / 256, 256, 0, stream>>>(ea, src, perm, ea_s, src_s);

        // K-split embedding GEMM + reduce
        k_emb_part<<<313 * 8, 256, 0, stream>>>(x, W_emb, hpart);
        k_emb_reduce<<<2500, 256, 0, stream>>>(hpart, b_emb, h);

        // layer 0: gene transform + fused per-node message/aggregate + update
        k_gene<<<NGENES / 4, 256, 0, stream>>>(h, msg_W, msg_b, smax, G);
        k_fusedagg<<<N_NODES / 4, 256, 0, stream>>>(G, msg_W, P, ea_s, src_s,
                                                    row_start, smax, aggr);
        k_upd_f32<<<313, 512, 0, stream>>>(aggr, h, upd_W, upd_b);
        // layer 1
        k_gene<<<NGENES / 4, 256, 0, stream>>>(h, msg_W + 160 * PD, msg_b + PD, smax, G);
        k_fusedagg<<<N_NODES / 4, 256, 0, stream>>>(G, msg_W + 160 * PD, P, ea_s, src_s,
                                                    row_start, smax, aggr);
        k_upd_f32<<<313, 512, 0, stream>>>(aggr, h, upd_W + 192 * EMB, upd_b + EMB);

        // heads
        k_node_pn<<<(N_NODES + 255) / 256, 256, 0, stream>>>(h, W_node, b_node, W_ep,
                                                             out, pn1, pn2);
        k_edge2<<<NEDGE / 256, 256, 0, stream>>>(ea, src, dst, pn1, pn2, W_ep, b_ep,
                                                 out + (size_t)N_NODES * OUTD);
    } else {
        // fallback: atomic scatter path
        k_srcmax<<<NEDGE / 256, 256, 0, stream>>>(src, smax);
        k_emb_f32<<<313 * 2, 256, 0, stream>>>(x, W_emb, b_emb, h);
        hipMemsetAsync(aggr, 0, (size_t)N_NODES * PD * 4, stream);
        k_msg_f32<<<NEDGE / 256, 256, 0, stream>>>(h, ea, src, dst, msg_W, msg_b, P, smax, aggr);
        k_upd_f32<<<313, 512, 0, stream>>>(aggr, h, upd_W, upd_b);
        hipMemsetAsync(aggr, 0, (size_t)N_NODES * PD * 4, stream);
        k_msg_f32<<<NEDGE / 256, 256, 0, stream>>>(h, ea, src, dst,
                                                   msg_W + 160 * PD, msg_b + PD, P, smax, aggr);
        k_upd_f32<<<313, 512, 0, stream>>>(aggr, h, upd_W + 192 * EMB, upd_b + EMB);
        k_node_f32<<<(N_NODES + 255) / 256, 256, 0, stream>>>(h, W_node, b_node, out);
        k_edge_f32<<<NEDGE / 256, 256, 0, stream>>>(h, ea, src, dst, W_ep, b_ep,
                                                    out + (size_t)N_NODES * OUTD);
    }
}

// Round 6
// 995.914 us; speedup vs baseline: 5.4199x; 1.2204x over previous
//
#include <hip/hip_runtime.h>
#include <hip/hip_bf16.h>

typedef float f32x4 __attribute__((ext_vector_type(4)));

#define N_NODES 20000
#define NGENES  2000
#define NEDGE   640000
#define EMB     128
#define ED      32
#define PD      64
#define OUTD    16
#define KEMB    2000

// ---------------- fused: max(src) + dst histogram ----------------
__global__ __launch_bounds__(256) void k_prep(const int* __restrict__ src,
                                              const int* __restrict__ dst,
                                              int* __restrict__ smax,
                                              int* __restrict__ cnt) {
    __shared__ int sm[256];
    int i = blockIdx.x * 256 + threadIdx.x;
    int s = src[i];
    atomicAdd(&cnt[dst[i]], 1);
    sm[threadIdx.x] = s;
    __syncthreads();
    for (int st = 128; st > 0; st >>= 1) {
        if (threadIdx.x < st) sm[threadIdx.x] = max(sm[threadIdx.x], sm[threadIdx.x + st]);
        __syncthreads();
    }
    if (threadIdx.x == 0) atomicMax(smax, sm[0]);
}

// ---------------- fallback srcmax ----------------
__global__ __launch_bounds__(256) void k_srcmax(const int* __restrict__ src,
                                                int* __restrict__ out) {
    __shared__ int sm[256];
    int i = blockIdx.x * 256 + threadIdx.x;
    sm[threadIdx.x] = (i < NEDGE) ? src[i] : 0;
    __syncthreads();
    for (int s = 128; s > 0; s >>= 1) {
        if (threadIdx.x < s) sm[threadIdx.x] = max(sm[threadIdx.x], sm[threadIdx.x + s]);
        __syncthreads();
    }
    if (threadIdx.x == 0) atomicMax(out, sm[0]);
}

// single-block exclusive scan over 20000 bins -> row_start[0..N], cursor[i]=row_start[i]
__global__ __launch_bounds__(1024) void k_scan(const int* __restrict__ cnt,
                                               int* __restrict__ row_start,
                                               int* __restrict__ cursor) {
    __shared__ int a[1024], b[1024];
    __shared__ int carry_s;
    int tid = threadIdx.x;
    if (tid == 0) carry_s = 0;
    __syncthreads();
    for (int chunk = 0; chunk < (N_NODES + 1023) / 1024; ++chunk) {
        int i = chunk * 1024 + tid;
        int v = (i < N_NODES) ? cnt[i] : 0;
        a[tid] = v;
        __syncthreads();
        int* s_ = a; int* d_ = b;
        for (int off = 1; off < 1024; off <<= 1) {
            int val = s_[tid];
            if (tid >= off) val += s_[tid - off];
            d_[tid] = val;
            __syncthreads();
            int* t = s_; s_ = d_; d_ = t;
        }
        int incl = s_[tid];
        int carry = carry_s;
        if (i < N_NODES) {
            row_start[i + 1] = carry + incl;
            cursor[i] = carry + incl - v;
        }
        __syncthreads();
        if (tid == 1023) carry_s = carry + incl;
        __syncthreads();
    }
    if (tid == 0) row_start[0] = 0;
}

// scatter: perm + sorted src in one pass
__global__ __launch_bounds__(256) void k_scatter(const int* __restrict__ src,
                                                 const int* __restrict__ dst,
                                                 int* __restrict__ cursor,
                                                 int* __restrict__ perm,
                                                 int* __restrict__ src_s) {
    int e = blockIdx.x * 256 + threadIdx.x;
    int pos = atomicAdd(&cursor[dst[e]], 1);
    perm[pos] = e;
    src_s[pos] = src[e];
}

// ---------------- K-split embedding GEMM: hpart[ks] = x[:,ksel] @ W[ksel,:] ----------------
__global__ __launch_bounds__(256) void k_emb_part(const float* __restrict__ x,
                                                  const float* __restrict__ W,   // [2000][128]
                                                  float* __restrict__ hpart) {
    __shared__ float As[64 * 17];
    __shared__ float Bs[16 * 64];
    int tid = threadIdx.x;
    int b = blockIdx.x;
    int ks = b & 3, nt = (b >> 2) & 1, mt = b >> 3;
    int row0 = mt * 64, n0 = nt * 64;
    int kt0 = ks * 32, kt1 = min(125, kt0 + 32);
    int tx = tid & 15, ty = tid >> 4;
    float acc[4][4] = {};
    int ar = tid >> 2, ac = (tid & 3) * 4;
    int bkr = tid >> 4, bc = (tid & 15) * 4;
    for (int kt = kt0; kt < kt1; ++kt) {
        int k0 = kt * 16;
        if (row0 + ar < N_NODES) {
            f32x4 av = *(const f32x4*)(x + (long)(row0 + ar) * KEMB + k0 + ac);
#pragma unroll
            for (int j = 0; j < 4; ++j) As[ar * 17 + ac + j] = av[j];
        } else {
#pragma unroll
            for (int j = 0; j < 4; ++j) As[ar * 17 + ac + j] = 0.f;
        }
        *(f32x4*)(Bs + bkr * 64 + bc) = *(const f32x4*)(W + (long)(k0 + bkr) * EMB + n0 + bc);
        __syncthreads();
#pragma unroll 1
        for (int kk = 0; kk < 16; ++kk) {
            float a[4];
#pragma unroll
            for (int i = 0; i < 4; ++i) a[i] = As[(ty * 4 + i) * 17 + kk];
            f32x4 bv = *(const f32x4*)(Bs + kk * 64 + tx * 4);
#pragma unroll
            for (int i = 0; i < 4; ++i)
#pragma unroll
                for (int j = 0; j < 4; ++j) acc[i][j] += a[i] * bv[j];
        }
        __syncthreads();
    }
    float* hp = hpart + (size_t)ks * N_NODES * EMB;
#pragma unroll
    for (int i = 0; i < 4; ++i) {
        int row = row0 + ty * 4 + i;
        if (row >= N_NODES) continue;
        f32x4 o;
#pragma unroll
        for (int j = 0; j < 4; ++j) o[j] = acc[i][j];
        *(f32x4*)(hp + (long)row * EMB + n0 + tx * 4) = o;
    }
}

// h = sum_{ks} hpart[ks] + bias  (deterministic)
__global__ __launch_bounds__(256) void k_emb_reduce(const float* __restrict__ hpart,
                                                    const float* __restrict__ bias,
                                                    float* __restrict__ h) {
    long i = (long)blockIdx.x * 256 + threadIdx.x;
    long p = i * 4;
    int c = (int)(p & 127);
    f32x4 a0 = *(const f32x4*)(hpart + p);
    f32x4 a1 = *(const f32x4*)(hpart + (size_t)N_NODES * EMB + p);
    f32x4 a2 = *(const f32x4*)(hpart + 2 * (size_t)N_NODES * EMB + p);
    f32x4 a3 = *(const f32x4*)(hpart + 3 * (size_t)N_NODES * EMB + p);
    f32x4 bb = *(const f32x4*)(bias + c);
    f32x4 o;
#pragma unroll
    for (int j = 0; j < 4; ++j) o[j] = (a0[j] + a1[j]) + (a2[j] + a3[j]) + bb[j];
    *(f32x4*)(h + p) = o;
}

// ---------------- fallback monolithic embedding GEMM ----------------
__global__ __launch_bounds__(256) void k_emb_f32(const float* __restrict__ x,
                                                 const float* __restrict__ W,
                                                 const float* __restrict__ bias,
                                                 float* __restrict__ h) {
    __shared__ float As[64 * 17];
    __shared__ float Bs[16 * 64];
    int tid = threadIdx.x;
    int mt = blockIdx.x >> 1, nt = blockIdx.x & 1;
    int row0 = mt * 64, n0 = nt * 64;
    int tx = tid & 15, ty = tid >> 4;
    float acc[4][4] = {};
    int ar = tid >> 2, ac = (tid & 3) * 4;
    int bkr = tid >> 4, bc = (tid & 15) * 4;
    for (int kt = 0; kt < 125; ++kt) {
        int k0 = kt * 16;
        if (row0 + ar < N_NODES) {
            f32x4 av = *(const f32x4*)(x + (long)(row0 + ar) * KEMB + k0 + ac);
#pragma unroll
            for (int j = 0; j < 4; ++j) As[ar * 17 + ac + j] = av[j];
        } else {
#pragma unroll
            for (int j = 0; j < 4; ++j) As[ar * 17 + ac + j] = 0.f;
        }
        *(f32x4*)(Bs + bkr * 64 + bc) = *(const f32x4*)(W + (long)(k0 + bkr) * EMB + n0 + bc);
        __syncthreads();
#pragma unroll 1
        for (int kk = 0; kk < 16; ++kk) {
            float a[4];
#pragma unroll
            for (int i = 0; i < 4; ++i) a[i] = As[(ty * 4 + i) * 17 + kk];
            f32x4 bv = *(const f32x4*)(Bs + kk * 64 + tx * 4);
#pragma unroll
            for (int i = 0; i < 4; ++i)
#pragma unroll
                for (int j = 0; j < 4; ++j) acc[i][j] += a[i] * bv[j];
        }
        __syncthreads();
    }
#pragma unroll
    for (int i = 0; i < 4; ++i) {
        int row = row0 + ty * 4 + i;
        if (row >= N_NODES) continue;
        f32x4 o;
#pragma unroll
        for (int j = 0; j < 4; ++j) o[j] = acc[i][j] + bias[n0 + tx * 4 + j];
        *(f32x4*)(h + (long)row * EMB + n0 + tx * 4) = o;
    }
}

// ---------------- per-gene transform: G[g] = h[base+g] @ W_h + mb ----------------
__global__ __launch_bounds__(256) void k_gene(const float* __restrict__ h,
                                              const float* __restrict__ mW,   // [160][64]
                                              const float* __restrict__ mb,   // [64]
                                              const int* __restrict__ smax,
                                              float* __restrict__ G) {
    __shared__ float Ws[128 * 64];
    __shared__ float hs[4][128];
    int tid = threadIdx.x;
    for (int i = tid; i < 2048; i += 256)
        *(f32x4*)(Ws + i * 4) = *(const f32x4*)(mW + i * 4);
    int base = *smax - (NGENES - 1);
    int g0 = blockIdx.x * 4;
    for (int i = tid; i < 128; i += 256) {
        int r = i >> 5, c = (i & 31) * 4;
        *(f32x4*)(&hs[r][c]) = *(const f32x4*)(h + (long)(base + g0 + r) * EMB + c);
    }
    __syncthreads();
    int wv = tid >> 6, lane = tid & 63;
    float a0 = mb[lane], a1 = 0.f, a2 = 0.f, a3 = 0.f;
#pragma unroll 8
    for (int k = 0; k < 128; k += 4) {
        a0 += hs[wv][k + 0] * Ws[(k + 0) * 64 + lane];
        a1 += hs[wv][k + 1] * Ws[(k + 1) * 64 + lane];
        a2 += hs[wv][k + 2] * Ws[(k + 2) * 64 + lane];
        a3 += hs[wv][k + 3] * Ws[(k + 3) * 64 + lane];
    }
    G[(long)(g0 + wv) * PD + lane] = (a0 + a1) + (a2 + a3);
}

// ---------------- message materialize: tile GEMM over edges ----------------
// m[j] = relu(G[g_j] + ea[perm[j]] @ We) * P[g_j], row-major [E][64], coalesced.
// Block = 64 edges, 256 threads (16x16), K=32.
__global__ __launch_bounds__(256) void k_msgmat(const float* __restrict__ ea,
                                                const int* __restrict__ perm,
                                                const int* __restrict__ src_s,
                                                const float* __restrict__ mW,   // [160][64]
                                                const float* __restrict__ G,    // [2000][64]
                                                const float* __restrict__ P,    // [2000][64]
                                                const int* __restrict__ smax,
                                                float* __restrict__ m) {
    __shared__ float EA[64 * 33];
    __shared__ float Ws[32 * 64];
    int tid = threadIdx.x;
    int e0 = blockIdx.x * 64;
    // stage We (rows 128..159 of mW, contiguous 2048 floats)
    for (int i = tid; i < 512; i += 256)
        *(f32x4*)(Ws + i * 4) = *(const f32x4*)(mW + 128 * 64 + i * 4);
    // stage EA gathered rows (64 rows x 32 floats)
    for (int i = tid; i < 512; i += 256) {
        int r = i >> 3, c = (i & 7) * 4;
        int e = perm[e0 + r];
        f32x4 v = *(const f32x4*)(ea + (long)e * ED + c);
        EA[r * 33 + c + 0] = v[0];
        EA[r * 33 + c + 1] = v[1];
        EA[r * 33 + c + 2] = v[2];
        EA[r * 33 + c + 3] = v[3];
    }
    __syncthreads();
    int tx = tid & 15, ty = tid >> 4;   // ty: 4-edge group, tx: 4-channel group
    float acc[4][4] = {};
#pragma unroll
    for (int k = 0; k < 32; ++k) {
        float a[4];
#pragma unroll
        for (int i = 0; i < 4; ++i) a[i] = EA[(ty * 4 + i) * 33 + k];
        f32x4 bv = *(const f32x4*)(Ws + k * 64 + tx * 4);
#pragma unroll
        for (int i = 0; i < 4; ++i)
#pragma unroll
            for (int j = 0; j < 4; ++j) acc[i][j] += a[i] * bv[j];
    }
    int base = *smax - (NGENES - 1);
#pragma unroll
    for (int i = 0; i < 4; ++i) {
        int j = e0 + ty * 4 + i;
        int g = src_s[j] - base;
        f32x4 Gv = *(const f32x4*)(G + (long)g * PD + tx * 4);
        f32x4 Pv = *(const f32x4*)(P + (long)g * PD + tx * 4);
        f32x4 o;
#pragma unroll
        for (int jj = 0; jj < 4; ++jj)
            o[jj] = fmaxf(acc[i][jj] + Gv[jj], 0.f) * Pv[jj];
        *(f32x4*)(m + (long)j * PD + tx * 4) = o;
    }
}

// ---------------- aggregate: one wave per node, contiguous segment sum ----------------
__global__ __launch_bounds__(256) void k_sumagg(const float* __restrict__ m,
                                                const int* __restrict__ row_start,
                                                float* __restrict__ aggr) {
    int n = blockIdx.x * 4 + (threadIdx.x >> 6);
    int lane = threadIdx.x & 63;
    if (n >= N_NODES) return;
    int j0 = row_start[n], j1 = row_start[n + 1];
    float acc0 = 0.f, acc1 = 0.f;
    int j = j0;
    for (; j + 1 < j1; j += 2) {
        acc0 += m[(long)j * PD + lane];
        acc1 += m[(long)(j + 1) * PD + lane];
    }
    if (j < j1) acc0 += m[(long)j * PD + lane];
    aggr[(long)n * PD + lane] = acc0 + acc1;
}

// ---------------- fallback fused message (atomic scatter) ----------------
__global__ __launch_bounds__(256) void k_msg_f32(const float* __restrict__ h,
                                                 const float* __restrict__ ea,
                                                 const int* __restrict__ src,
                                                 const int* __restrict__ dst,
                                                 const float* __restrict__ mW,
                                                 const float* __restrict__ mb,
                                                 const float* __restrict__ P,
                                                 const int* __restrict__ smax,
                                                 float* __restrict__ aggr) {
    int e = blockIdx.x * 256 + threadIdx.x;
    int s = src[e], d = dst[e];
    float acc[PD];
#pragma unroll
    for (int o = 0; o < PD; ++o) acc[o] = mb[o];
#pragma unroll 1
    for (int kb = 0; kb < 10; ++kb) {
        float in[16];
        if (kb < 8) {
            f32x4 v0 = *(const f32x4*)(h + (long)s * EMB + kb * 16);
            f32x4 v1 = *(const f32x4*)(h + (long)s * EMB + kb * 16 + 4);
            f32x4 v2 = *(const f32x4*)(h + (long)s * EMB + kb * 16 + 8);
            f32x4 v3 = *(const f32x4*)(h + (long)s * EMB + kb * 16 + 12);
#pragma unroll
            for (int j = 0; j < 4; ++j) { in[j] = v0[j]; in[4+j] = v1[j]; in[8+j] = v2[j]; in[12+j] = v3[j]; }
        } else {
            f32x4 v0 = *(const f32x4*)(ea + (long)e * ED + (kb - 8) * 16);
            f32x4 v1 = *(const f32x4*)(ea + (long)e * ED + (kb - 8) * 16 + 4);
            f32x4 v2 = *(const f32x4*)(ea + (long)e * ED + (kb - 8) * 16 + 8);
            f32x4 v3 = *(const f32x4*)(ea + (long)e * ED + (kb - 8) * 16 + 12);
#pragma unroll
            for (int j = 0; j < 4; ++j) { in[j] = v0[j]; in[4+j] = v1[j]; in[8+j] = v2[j]; in[12+j] = v3[j]; }
        }
#pragma unroll 1
        for (int kk = 0; kk < 16; ++kk) {
            const float* wrow = mW + (long)(kb * 16 + kk) * PD;
            float v = in[kk];
#pragma unroll
            for (int o = 0; o < PD; ++o) acc[o] += v * wrow[o];
        }
    }
    int base = *smax - (NGENES - 1);
    const float* Pe = P + (long)(s - base) * PD;
    float* arow = aggr + (long)d * PD;
#pragma unroll
    for (int o = 0; o < PD; ++o) {
        float v = fmaxf(acc[o], 0.f) * Pe[o];
        unsafeAtomicAdd(arow + o, v);
    }
}

// ---------------- update f32 (in-place h): h = relu(cat(aggr,h) @ W + b) ----------------
__global__ __launch_bounds__(512) void k_upd_f32(const float* __restrict__ aggr,
                                                 float* __restrict__ h,
                                                 const float* __restrict__ uW,  // [192][128]
                                                 const float* __restrict__ ub)  // [128]
{
    __shared__ float lds[64 * 193];
    int tid = threadIdx.x;
    int n0 = blockIdx.x * 64;
    for (int i = tid; i < 64 * 64; i += 512) {
        int nl = i >> 6, k = i & 63;
        lds[nl * 193 + k] = (n0 + nl < N_NODES) ? aggr[(long)(n0 + nl) * PD + k] : 0.f;
    }
    for (int i = tid; i < 64 * 128; i += 512) {
        int nl = i >> 7, k = i & 127;
        lds[nl * 193 + 64 + k] = (n0 + nl < N_NODES) ? h[(long)(n0 + nl) * EMB + k] : 0.f;
    }
    __syncthreads();
    int wv = tid >> 6, l = tid & 63;
    int o0 = wv * 16;
    int n = n0 + l;
    float acc[16];
#pragma unroll
    for (int o = 0; o < 16; ++o) acc[o] = ub[o0 + o];
#pragma unroll 4
    for (int k = 0; k < 192; ++k) {
        float v = lds[l * 193 + k];
        const float* wrow = uW + (long)k * EMB + o0;
#pragma unroll
        for (int o = 0; o < 16; ++o) acc[o] += v * wrow[o];
    }
    if (n < N_NODES) {
#pragma unroll
        for (int c = 0; c < 4; ++c) {
            f32x4 v;
#pragma unroll
            for (int j = 0; j < 4; ++j) v[j] = fmaxf(acc[c * 4 + j], 0.f);
            *(f32x4*)(h + (long)n * EMB + o0 + c * 4) = v;
        }
    }
}

// ---------------- node head + per-node edge projections ----------------
__global__ __launch_bounds__(256) void k_node_pn(const float* __restrict__ h,
                                                 const float* __restrict__ W,  // [128][16]
                                                 const float* __restrict__ b,
                                                 const float* __restrict__ Wep, // [288]
                                                 float* __restrict__ out,
                                                 float* __restrict__ pn1,
                                                 float* __restrict__ pn2) {
    int n = blockIdx.x * 256 + threadIdx.x;
    if (n >= N_NODES) return;
    float acc[OUTD];
#pragma unroll
    for (int o = 0; o < OUTD; ++o) acc[o] = b[o];
    float p1a = 0.f, p1b = 0.f, p2a = 0.f, p2b = 0.f;
#pragma unroll 1
    for (int kb = 0; kb < 32; ++kb) {
        f32x4 hv = *(const f32x4*)(h + (long)n * EMB + kb * 4);
#pragma unroll
        for (int j = 0; j < 4; ++j) {
            const float* wrow = W + (long)(kb * 4 + j) * OUTD;
#pragma unroll
            for (int o = 0; o < OUTD; ++o) acc[o] += hv[j] * wrow[o];
        }
        p1a += hv[0] * Wep[kb * 4 + 0] + hv[1] * Wep[kb * 4 + 1];
        p1b += hv[2] * Wep[kb * 4 + 2] + hv[3] * Wep[kb * 4 + 3];
        p2a += hv[0] * Wep[128 + kb * 4 + 0] + hv[1] * Wep[128 + kb * 4 + 1];
        p2b += hv[2] * Wep[128 + kb * 4 + 2] + hv[3] * Wep[128 + kb * 4 + 3];
    }
#pragma unroll
    for (int c = 0; c < 4; ++c) {
        f32x4 v;
#pragma unroll
        for (int j = 0; j < 4; ++j) v[j] = acc[c * 4 + j];
        *(f32x4*)(out + (long)n * OUTD + c * 4) = v;
    }
    pn1[n] = p1a + p1b;
    pn2[n] = p2a + p2b;
}

// ---------------- fallback node head ----------------
__global__ __launch_bounds__(256) void k_node_f32(const float* __restrict__ h,
                                                  const float* __restrict__ W,
                                                  const float* __restrict__ b,
                                                  float* __restrict__ out) {
    int n = blockIdx.x * 256 + threadIdx.x;
    if (n >= N_NODES) return;
    float acc[OUTD];
#pragma unroll
    for (int o = 0; o < OUTD; ++o) acc[o] = b[o];
#pragma unroll 1
    for (int kb = 0; kb < 32; ++kb) {
        f32x4 hv = *(const f32x4*)(h + (long)n * EMB + kb * 4);
#pragma unroll
        for (int j = 0; j < 4; ++j) {
            const float* wrow = W + (long)(kb * 4 + j) * OUTD;
#pragma unroll
            for (int o = 0; o < OUTD; ++o) acc[o] += hv[j] * wrow[o];
        }
    }
#pragma unroll
    for (int c = 0; c < 4; ++c) {
        f32x4 v;
#pragma unroll
        for (int j = 0; j < 4; ++j) v[j] = acc[c * 4 + j];
        *(f32x4*)(out + (long)n * OUTD + c * 4) = v;
    }
}

// ---------------- edge head via precomputed node projections ----------------
__global__ __launch_bounds__(256) void k_edge2(const float* __restrict__ ea,
                                               const int* __restrict__ src,
                                               const int* __restrict__ dstv,
                                               const float* __restrict__ pn1,
                                               const float* __restrict__ pn2,
                                               const float* __restrict__ Wep, // [288]
                                               const float* __restrict__ bep,
                                               float* __restrict__ out) {
    int e = blockIdx.x * 256 + threadIdx.x;
    float a0 = bep[0] + pn1[src[e]] + pn2[dstv[e]];
    float a1 = 0.f, a2 = 0.f, a3 = 0.f;
#pragma unroll
    for (int kb = 0; kb < 8; ++kb) {
        f32x4 av = *(const f32x4*)(ea + (long)e * ED + kb * 4);
        a0 += av[0] * Wep[256 + kb * 4 + 0];
        a1 += av[1] * Wep[256 + kb * 4 + 1];
        a2 += av[2] * Wep[256 + kb * 4 + 2];
        a3 += av[3] * Wep[256 + kb * 4 + 3];
    }
    out[e] = (a0 + a1) + (a2 + a3);
}

// ---------------- fallback edge head ----------------
__global__ __launch_bounds__(256) void k_edge_f32(const float* __restrict__ h,
                                                  const float* __restrict__ ea,
                                                  const int* __restrict__ src,
                                                  const int* __restrict__ dst,
                                                  const float* __restrict__ Wep,
                                                  const float* __restrict__ bep,
                                                  float* __restrict__ out) {
    int e = blockIdx.x * 256 + threadIdx.x;
    int s = src[e], d = dst[e];
    float a0 = bep[0], a1 = 0.f, a2 = 0.f, a3 = 0.f;
#pragma unroll 1
    for (int kb = 0; kb < 32; ++kb) {
        f32x4 hv = *(const f32x4*)(h + (long)s * EMB + kb * 4);
        a0 += hv[0] * Wep[kb * 4 + 0];
        a1 += hv[1] * Wep[kb * 4 + 1];
        a2 += hv[2] * Wep[kb * 4 + 2];
        a3 += hv[3] * Wep[kb * 4 + 3];
    }
#pragma unroll 1
    for (int kb = 0; kb < 32; ++kb) {
        f32x4 hv = *(const f32x4*)(h + (long)d * EMB + kb * 4);
        a0 += hv[0] * Wep[128 + kb * 4 + 0];
        a1 += hv[1] * Wep[128 + kb * 4 + 1];
        a2 += hv[2] * Wep[128 + kb * 4 + 2];
        a3 += hv[3] * Wep[128 + kb * 4 + 3];
    }
#pragma unroll 1
    for (int kb = 0; kb < 8; ++kb) {
        f32x4 av = *(const f32x4*)(ea + (long)e * ED + kb * 4);
        a0 += av[0] * Wep[256 + kb * 4 + 0];
        a1 += av[1] * Wep[256 + kb * 4 + 1];
        a2 += av[2] * Wep[256 + kb * 4 + 2];
        a3 += av[3] * Wep[256 + kb * 4 + 3];
    }
    out[e] = (a0 + a1) + (a2 + a3);
}

extern "C" void kernel_launch(void* const* d_in, const int* in_sizes, int n_in,
                              void* d_out, int out_size, void* d_ws, size_t ws_size,
                              hipStream_t stream) {
    const float* x      = (const float*)d_in[0];
    const float* ea     = (const float*)d_in[1];
    const int*   eidx   = (const int*)d_in[2];
    const float* W_emb  = (const float*)d_in[3];
    const float* b_emb  = (const float*)d_in[4];
    const float* msg_W  = (const float*)d_in[5];
    const float* msg_b  = (const float*)d_in[6];
    const float* upd_W  = (const float*)d_in[7];
    const float* upd_b  = (const float*)d_in[8];
    const float* W_node = (const float*)d_in[9];
    const float* b_node = (const float*)d_in[10];
    const float* W_ep   = (const float*)d_in[11];
    const float* b_ep   = (const float*)d_in[12];
    const float* P      = (const float*)d_in[13];
    float* out = (float*)d_out;

    const int* src = eidx;
    const int* dst = eidx + NEDGE;

    // ---- base workspace ----
    size_t off = 0;
    char* w = (char*)d_ws;
    float* h    = (float*)(w + off); off += (size_t)N_NODES * EMB * 4;   // 10.24 MB
    float* aggr = (float*)(w + off); off += (size_t)N_NODES * PD * 4;    // 5.12 MB
    int*   smax = (int*)(w + off);   off += 16;
    if (ws_size < off) return;

    // ---- extended (sorted, materialized-message) layout ----
    size_t off2 = off;
    int* cnt       = (int*)(w + off2); off2 += (size_t)N_NODES * 4;
    int* row_start = (int*)(w + off2); off2 += ((size_t)(N_NODES + 1) * 4 + 15) & ~15ull;
    int* cursor    = (int*)(w + off2); off2 += (size_t)N_NODES * 4;
    int* perm      = (int*)(w + off2); off2 += (size_t)NEDGE * 4;          // 2.56 MB
    int* src_s     = (int*)(w + off2); off2 += (size_t)NEDGE * 4;          // 2.56 MB
    float* pn1     = (float*)(w + off2); off2 += (size_t)N_NODES * 4;
    float* pn2     = (float*)(w + off2); off2 += (size_t)N_NODES * 4;
    float* G       = (float*)(w + off2); off2 += (size_t)NGENES * PD * 4;  // 0.51 MB
    float* m       = (float*)(w + off2); off2 += (size_t)NEDGE * PD * 4;   // 163.84 MB
    float* hpart   = m;  // overlay: hpart (40.96 MB) dead before m is written
    const bool fast = (ws_size >= off2);   // ~185.5 MB total

    hipMemsetAsync(smax, 0, 4, stream);

    if (fast) {
        // CSR build (dst constant across both layers); scatter writes perm + sorted src
        hipMemsetAsync(cnt, 0, (size_t)N_NODES * 4, stream);
        k_prep<<<NEDGE / 256, 256, 0, stream>>>(src, dst, smax, cnt);
        k_scan<<<1, 1024, 0, stream>>>(cnt, row_start, cursor);
        k_scatter<<<NEDGE / 256, 256, 0, stream>>>(src, dst, cursor, perm, src_s);

        // K-split embedding GEMM + reduce (hpart overlays m)
        k_emb_part<<<313 * 8, 256, 0, stream>>>(x, W_emb, hpart);
        k_emb_reduce<<<2500, 256, 0, stream>>>(hpart, b_emb, h);

        // layer 0: gene transform + message GEMM + stream-sum + update
        k_gene<<<NGENES / 4, 256, 0, stream>>>(h, msg_W, msg_b, smax, G);
        k_msgmat<<<NEDGE / 64, 256, 0, stream>>>(ea, perm, src_s, msg_W, G, P, smax, m);
        k_sumagg<<<N_NODES / 4, 256, 0, stream>>>(m, row_start, aggr);
        k_upd_f32<<<313, 512, 0, stream>>>(aggr, h, upd_W, upd_b);
        // layer 1
        k_gene<<<NGENES / 4, 256, 0, stream>>>(h, msg_W + 160 * PD, msg_b + PD, smax, G);
        k_msgmat<<<NEDGE / 64, 256, 0, stream>>>(ea, perm, src_s, msg_W + 160 * PD, G, P, smax, m);
        k_sumagg<<<N_NODES / 4, 256, 0, stream>>>(m, row_start, aggr);
        k_upd_f32<<<313, 512, 0, stream>>>(aggr, h, upd_W + 192 * EMB, upd_b + EMB);

        // heads
        k_node_pn<<<(N_NODES + 255) / 256, 256, 0, stream>>>(h, W_node, b_node, W_ep,
                                                             out, pn1, pn2);
        k_edge2<<<NEDGE / 256, 256, 0, stream>>>(ea, src, dst, pn1, pn2, W_ep, b_ep,
                                                 out + (size_t)N_NODES * OUTD);
    } else {
        // fallback: atomic scatter path
        k_srcmax<<<NEDGE / 256, 256, 0, stream>>>(src, smax);
        k_emb_f32<<<313 * 2, 256, 0, stream>>>(x, W_emb, b_emb, h);
        hipMemsetAsync(aggr, 0, (size_t)N_NODES * PD * 4, stream);
        k_msg_f32<<<NEDGE / 256, 256, 0, stream>>>(h, ea, src, dst, msg_W, msg_b, P, smax, aggr);
        k_upd_f32<<<313, 512, 0, stream>>>(aggr, h, upd_W, upd_b);
        hipMemsetAsync(aggr, 0, (size_t)N_NODES * PD * 4, stream);
        k_msg_f32<<<NEDGE / 256, 256, 0, stream>>>(h, ea, src, dst,
                                                   msg_W + 160 * PD, msg_b + PD, P, smax, aggr);
        k_upd_f32<<<313, 512, 0, stream>>>(aggr, h, upd_W + 192 * EMB, upd_b + EMB);
        k_node_f32<<<(N_NODES + 255) / 256, 256, 0, stream>>>(h, W_node, b_node, out);
        k_edge_f32<<<NEDGE / 256, 256, 0, stream>>>(h, ea, src, dst, W_ep, b_ep,
                                                    out + (size_t)N_NODES * OUTD);
    }
}